// Round 14
// baseline (1399.283 us; speedup 1.0000x reference)
//
#include <hip/hip_runtime.h>

#define NB 8
#define NP 2048
#define KNN 20
#define EPSF 1e-6f

typedef unsigned short u16;
typedef __bf16 bfx8 __attribute__((ext_vector_type(8)));
typedef float f32x4 __attribute__((ext_vector_type(4)));

__device__ __forceinline__ u16 f2bf(float x) {
  unsigned u = __float_as_uint(x);
  unsigned r = u + 0x7FFFu + ((u >> 16) & 1u);
  return (u16)(r >> 16);
}
__device__ __forceinline__ float bf2f(u16 h) { return __uint_as_float(((unsigned)h) << 16); }

// ---------------- fused prep: transpose + weight splits + wcatT ------------
__device__ __forceinline__ void wsplit_one(const float* __restrict__ W, int Co, int Cstride,
                                           int Ccopy, int KP, long e, u16* __restrict__ H,
                                           u16* __restrict__ L) {
  int r = (int)(e / KP), c = (int)(e - (long)r * KP);
  float v = (r < Co && c < Ccopy) ? W[(long)r * Cstride + c] : 0.f;
  u16 h = f2bf(v);
  H[e] = h;
  L[e] = f2bf(v - bf2f(h));
}
__device__ __forceinline__ void wcatT_one(const float* __restrict__ W,
                                          const float* __restrict__ Dm, int C, int Co, long e,
                                          float* __restrict__ WcT) {
  int R4 = 4 * Co;
  int c = (int)(e / R4);
  int rr = (int)(e - (long)c * R4);
  int g = rr / Co;
  int co = rr - g * Co;
  const float* M = (g < 2) ? W : Dm;
  long base = (long)co * 2 * C;
  WcT[e] = (g & 1) ? (M[base + C + c] - M[base + c]) : M[base + c];
}

#define SZ_XT 49152L
#define SZ_W5 73728L
#define SZ_WS1 135168L
#define SZ_WS2 67584L
#define SZ_WC1 84L
#define SZ_WC2 1764L
#define SZ_WC3 3528L
#define SZ_WC4 14280L
#define SZ_PREP (SZ_XT + SZ_W5 + 2 * SZ_WS1 + 2 * SZ_WS2 + SZ_WC1 + SZ_WC2 + SZ_WC3 + SZ_WC4)

__global__ __launch_bounds__(256) void k_prep(
    const float* __restrict__ x, float* __restrict__ xT, const float* __restrict__ W5,
    const float* __restrict__ Ws1, const float* __restrict__ Ds1,
    const float* __restrict__ Ws2, const float* __restrict__ Ds2, u16* __restrict__ W5h,
    u16* __restrict__ W5l, u16* __restrict__ Ws1h, u16* __restrict__ Ws1l,
    u16* __restrict__ Ds1h, u16* __restrict__ Ds1l, u16* __restrict__ Ws2h,
    u16* __restrict__ Ws2l, u16* __restrict__ Ds2h, u16* __restrict__ Ds2l,
    const float* __restrict__ W1, const float* __restrict__ D1, const float* __restrict__ W2,
    const float* __restrict__ D2, const float* __restrict__ W3, const float* __restrict__ D3w,
    const float* __restrict__ W4, const float* __restrict__ D4, float* __restrict__ wc1,
    float* __restrict__ wc2, float* __restrict__ wc3, float* __restrict__ wc4) {
  long e = (long)blockIdx.x * 256 + threadIdx.x;
  if (e < SZ_XT) {
    int n = (int)(e % NP);
    int r = (int)(e / NP);
    int d = r % 3, b = r / 3;
    xT[e] = x[((long)b * NP + n) * 3 + d];
    return;
  }
  e -= SZ_XT;
  if (e < SZ_W5) { wsplit_one(W5, 341, 169, 169, 192, e, W5h, W5l); return; }
  e -= SZ_W5;
  if (e < SZ_WS1) { wsplit_one(Ws1, 341, 682, 341, 352, e, Ws1h, Ws1l); return; }
  e -= SZ_WS1;
  if (e < SZ_WS1) { wsplit_one(Ds1, 341, 682, 341, 352, e, Ds1h, Ds1l); return; }
  e -= SZ_WS1;
  if (e < SZ_WS2) { wsplit_one(Ws2, 170, 341, 341, 352, e, Ws2h, Ws2l); return; }
  e -= SZ_WS2;
  if (e < SZ_WS2) { wsplit_one(Ds2, 170, 341, 341, 352, e, Ds2h, Ds2l); return; }
  e -= SZ_WS2;
  if (e < SZ_WC1) { wcatT_one(W1, D1, 1, 21, e, wc1); return; }
  e -= SZ_WC1;
  if (e < SZ_WC2) { wcatT_one(W2, D2, 21, 21, e, wc2); return; }
  e -= SZ_WC2;
  if (e < SZ_WC3) { wcatT_one(W3, D3w, 21, 42, e, wc3); return; }
  e -= SZ_WC3;
  if (e < SZ_WC4) { wcatT_one(W4, D4, 42, 85, e, wc4); return; }
}

// ---------------- row squared norms ---------------------------------------
__global__ __launch_bounds__(256) void k_sqnorm(const float* __restrict__ X, long SB, int D3,
                                                float* __restrict__ sq) {
  int e = blockIdx.x * 256 + threadIdx.x;
  int b = e >> 11, n = e & (NP - 1);
  const float* Xb = X + (long)b * SB + n;
  float s = 0.f;
  for (int d = 0; d < D3; ++d) {
    float v = Xb[(long)d * NP];
    s += v * v;
  }
  sq[e] = s;
}

// ---------------- pairwise neg sq distance: 128x128 tile, 8x8/thread -------
#define KNN3_FMA                                                 \
  {                                                              \
    float ir[8], jr[8];                                          \
    *(float4*)&ir[0] = *(const float4*)&SI[cc * 128 + qi0 * 4];  \
    *(float4*)&ir[4] = *(const float4*)&SI[cc * 128 + qi1 * 4];  \
    *(float4*)&jr[0] = *(const float4*)&SJ[cc * 128 + qj0 * 4];  \
    *(float4*)&jr[4] = *(const float4*)&SJ[cc * 128 + qj1 * 4];  \
    _Pragma("unroll") for (int a = 0; a < 8; ++a)                \
        _Pragma("unroll") for (int c = 0; c < 8; ++c)            \
            acc[a][c] += ir[a] * jr[c];                          \
  }

__global__ __launch_bounds__(256) void k_knn3(const float* __restrict__ X, long SB, int D3,
                                              const float* __restrict__ sq,
                                              float* __restrict__ nd) {
  __shared__ float SI[32 * 128], SJ[32 * 128];
  int tid = threadIdx.x;
  int ti = tid & 15, tj = tid >> 4;
  int i0 = blockIdx.y * 128, j0 = blockIdx.x * 128, b = blockIdx.z;
  const float* Xb = X + (long)b * SB;
  float acc[8][8];
#pragma unroll
  for (int a = 0; a < 8; ++a)
#pragma unroll
    for (int c = 0; c < 8; ++c) acc[a][c] = 0.f;
  int qi0 = (2 * ti) ^ ((2 * ti) >> 2), qi1 = (2 * ti + 1) ^ ((2 * ti + 1) >> 2);
  int qj0 = (2 * tj) ^ ((2 * tj) >> 2), qj1 = (2 * tj + 1) ^ ((2 * tj + 1) >> 2);
  for (int dc = 0; dc < D3; dc += 32) {
    int cend = min(32, D3 - dc);
    for (int e = tid; e < 1024; e += 256) {
      int q = e & 31, cc = e >> 5;
      int d = dc + cc;
      if (d < D3) {
        float4 vi = *(const float4*)(Xb + (long)d * NP + i0 + q * 4);
        float4 vj = *(const float4*)(Xb + (long)d * NP + j0 + q * 4);
        int qs = q ^ (q >> 2);
        *(float4*)&SI[cc * 128 + qs * 4] = vi;
        *(float4*)&SJ[cc * 128 + qs * 4] = vj;
      }
    }
    __syncthreads();
    if (cend == 32) {
#pragma unroll
      for (int cc = 0; cc < 32; ++cc) KNN3_FMA;
    } else {
      for (int cc = 0; cc < cend; ++cc) KNN3_FMA;
    }
    __syncthreads();
  }
  const float* sqb = sq + (long)b * NP;
  float sjr[8];
  *(float4*)&sjr[0] = *(const float4*)&sqb[j0 + tj * 8];
  *(float4*)&sjr[4] = *(const float4*)&sqb[j0 + tj * 8 + 4];
#pragma unroll
  for (int a = 0; a < 8; ++a) {
    int i = i0 + ti * 8 + a;
    float si = sqb[i];
    float o[8];
#pragma unroll
    for (int c = 0; c < 8; ++c) o[c] = 2.f * acc[a][c] - si - sjr[c];
    float* op = nd + ((long)b * NP + i) * NP + j0 + tj * 8;
    *(float4*)&op[0] = *(float4*)&o[0];
    *(float4*)&op[4] = *(float4*)&o[4];
  }
}

// ---------------- top-k (k=20): binary-search select on orderable u32 ------
__global__ __launch_bounds__(256) void k_topk4(const float* __restrict__ nd,
                                               int* __restrict__ idx) {
  int wid = threadIdx.x >> 6, lane = threadIdx.x & 63;
  long row = (long)blockIdx.x * 4 + wid;
  const float4* r4 = (const float4*)(nd + row * NP);
  unsigned v[32];
#pragma unroll
  for (int m = 0; m < 8; ++m) {
    float4 w4 = r4[m * 64 + lane];
    float ww[4] = {w4.x, w4.y, w4.z, w4.w};
#pragma unroll
    for (int c = 0; c < 4; ++c) {
      unsigned b = __float_as_uint(ww[c]);
      v[m * 4 + c] = b ^ (unsigned)(((int)b >> 31) | 0x80000000);
    }
  }
  unsigned p = 0;
  for (int bit = 31; bit >= 0; --bit) {
    unsigned cand = p | (1u << bit);
    int cnt = 0;
#pragma unroll
    for (int e = 0; e < 32; ++e) cnt += (int)__popcll(__ballot(v[e] >= cand));
    if (cnt >= KNN) p = cand;
  }
  int* op = idx + row * KNN;
  int base = 0;
#pragma unroll
  for (int m = 0; m < 8; ++m) {
#pragma unroll
    for (int c = 0; c < 4; ++c) {
      int e = m * 4 + c;
      bool pr = v[e] > p;
      unsigned long long mk = __ballot(pr);
      if (pr) {
        int pos = base + (int)__popcll(mk & ((1ull << lane) - 1ull));
        op[pos] = m * 256 + lane * 4 + c;
      }
      base += (int)__popcll(mk);
    }
  }
  int need = KNN - base;
  int tj[32];
#pragma unroll
  for (int m = 0; m < 8; ++m)
#pragma unroll
    for (int c = 0; c < 4; ++c) {
      int e = m * 4 + c;
      tj[e] = (v[e] == p) ? (m * 256 + lane * 4 + c) : (1 << 30);
    }
  int last = -1;
  while (need > 0) {
    int mn = 1 << 30;
#pragma unroll
    for (int e = 0; e < 32; ++e) {
      int t = tj[e];
      if (t > last && t < mn) mn = t;
    }
    for (int off = 32; off >= 1; off >>= 1) {
      int o = __shfl_xor(mn, off);
      if (o < mn) mn = o;
    }
    if (lane == 0) op[KNN - need] = mn;
    last = mn;
    --need;
  }
}

// ---------------- per-point GEMM (register-blocked): U[b][n][rr][d] --------
// 1-D grid; b = bid & 7 so each batch pins to one XCD (L2 affinity with edge).
__global__ __launch_bounds__(256) void k_gemm_u2(const float* __restrict__ X, long SB, int C,
                                                 const float* __restrict__ WcT, int R4,
                                                 float* __restrict__ U) {
  int bid = blockIdx.x;
  int b = bid & 7;
  int n0 = (bid >> 3) * 64;
  int tn = threadIdx.x & 15, tr = threadIdx.x >> 4;
  extern __shared__ float XS[];  // [3C][64]
  const float* Xb = X + (long)b * SB;
  int tot = 3 * C * 64;
  for (int e = threadIdx.x; e < tot; e += 256) {
    int nn = e & 63, rest = e >> 6;
    XS[e] = Xb[(long)rest * NP + n0 + nn];
  }
  __syncthreads();
  for (int rrb = tr * 4; rrb < R4; rrb += 64) {
    float acc[3][4][4];
#pragma unroll
    for (int d = 0; d < 3; ++d)
#pragma unroll
      for (int i = 0; i < 4; ++i)
#pragma unroll
        for (int j = 0; j < 4; ++j) acc[d][i][j] = 0.f;
    for (int c = 0; c < C; ++c) {
      float wv[4], x0[4], x1[4], x2[4];
      *(float4*)&wv[0] = *(const float4*)&WcT[(long)c * R4 + rrb];
      *(float4*)&x0[0] = *(const float4*)&XS[(c * 3 + 0) * 64 + tn * 4];
      *(float4*)&x1[0] = *(const float4*)&XS[(c * 3 + 1) * 64 + tn * 4];
      *(float4*)&x2[0] = *(const float4*)&XS[(c * 3 + 2) * 64 + tn * 4];
#pragma unroll
      for (int i = 0; i < 4; ++i) {
        float w = wv[i];
#pragma unroll
        for (int j = 0; j < 4; ++j) {
          acc[0][i][j] += w * x0[j];
          acc[1][i][j] += w * x1[j];
          acc[2][i][j] += w * x2[j];
        }
      }
    }
#pragma unroll
    for (int j = 0; j < 4; ++j) {
      float* Ub = U + (((long)b * NP + n0 + tn * 4 + j) * R4 + rrb) * 3;
#pragma unroll
      for (int i = 0; i < 4; ++i) {
        Ub[i * 3 + 0] = acc[0][i][j];
        Ub[i * 3 + 1] = acc[1][i][j];
        Ub[i * 3 + 2] = acc[2][i][j];
      }
    }
  }
}

// ---------------- edge aggregate (batch->XCD pinned) -----------------------
__global__ __launch_bounds__(256) void k_edge(const float* __restrict__ U, int R4, int Co,
                                              const int* __restrict__ idx,
                                              float* __restrict__ out, long SBo,
                                              u16* __restrict__ xth, u16* __restrict__ xtl,
                                              int c0) {
  int bid = blockIdx.x;
  int b = bid & 7;                 // batch -> XCD affinity: U[b] stays in one L2
  int n = (bid >> 3) * 4 + (threadIdx.x >> 6);
  int pt = b * NP + n;
  int lane = threadIdx.x & 63;
  const int* ip = idx + (long)pt * KNN;
  const float* Un = U + (long)pt * R4 * 3;
  int ch0 = lane, ch1 = lane + 64;
  bool h0 = ch0 < Co, h1 = ch1 < Co;
  float cp00 = 0, cp01 = 0, cp02 = 0, cd00 = 0, cd01 = 0, cd02 = 0;
  float cp10 = 0, cp11 = 0, cp12 = 0, cd10 = 0, cd11 = 0, cd12 = 0;
  if (h0) {
    cp00 = Un[(Co + ch0) * 3 + 0]; cp01 = Un[(Co + ch0) * 3 + 1]; cp02 = Un[(Co + ch0) * 3 + 2];
    cd00 = Un[(3 * Co + ch0) * 3 + 0]; cd01 = Un[(3 * Co + ch0) * 3 + 1]; cd02 = Un[(3 * Co + ch0) * 3 + 2];
  }
  if (h1) {
    cp10 = Un[(Co + ch1) * 3 + 0]; cp11 = Un[(Co + ch1) * 3 + 1]; cp12 = Un[(Co + ch1) * 3 + 2];
    cd10 = Un[(3 * Co + ch1) * 3 + 0]; cd11 = Un[(3 * Co + ch1) * 3 + 1]; cd12 = Un[(3 * Co + ch1) * 3 + 2];
  }
  float a00 = 0, a01 = 0, a02 = 0, a10 = 0, a11 = 0, a12 = 0;
  for (int kk = 0; kk < KNN; ++kk) {
    int j = ip[kk];
    const float* Uj = U + ((long)b * NP + j) * R4 * 3;
    if (h0) {
      float p0 = Uj[ch0 * 3 + 0] + cp00, p1 = Uj[ch0 * 3 + 1] + cp01, p2 = Uj[ch0 * 3 + 2] + cp02;
      float q0 = Uj[(2 * Co + ch0) * 3 + 0] + cd00, q1 = Uj[(2 * Co + ch0) * 3 + 1] + cd01,
            q2 = Uj[(2 * Co + ch0) * 3 + 2] + cd02;
      float dot = p0 * q0 + p1 * q1 + p2 * q2;
      float dsq = q0 * q0 + q1 * q1 + q2 * q2;
      float coef = dot < 0.f ? 0.8f * dot / (dsq + EPSF) : 0.f;
      a00 += p0 - coef * q0; a01 += p1 - coef * q1; a02 += p2 - coef * q2;
    }
    if (h1) {
      float p0 = Uj[ch1 * 3 + 0] + cp10, p1 = Uj[ch1 * 3 + 1] + cp11, p2 = Uj[ch1 * 3 + 2] + cp12;
      float q0 = Uj[(2 * Co + ch1) * 3 + 0] + cd10, q1 = Uj[(2 * Co + ch1) * 3 + 1] + cd11,
            q2 = Uj[(2 * Co + ch1) * 3 + 2] + cd12;
      float dot = p0 * q0 + p1 * q1 + p2 * q2;
      float dsq = q0 * q0 + q1 * q1 + q2 * q2;
      float coef = dot < 0.f ? 0.8f * dot / (dsq + EPSF) : 0.f;
      a10 += p0 - coef * q0; a11 += p1 - coef * q1; a12 += p2 - coef * q2;
    }
  }
  const float s = 1.f / KNN;
  if (h0) {
    float y0 = a00 * s, y1 = a01 * s, y2 = a02 * s;
    float* o = out + (long)b * SBo + (long)ch0 * 3 * NP + n;
    o[0] = y0; o[NP] = y1; o[2 * NP] = y2;
    int col = c0 + ch0;
    long r0 = ((long)b * 6144 + n) * 192 + col;
    float yv[3] = {y0, y1, y2};
#pragma unroll
    for (int d = 0; d < 3; ++d) {
      u16 h = f2bf(yv[d]);
      xth[r0 + (long)d * 2048 * 192] = h;
      xtl[r0 + (long)d * 2048 * 192] = f2bf(yv[d] - bf2f(h));
    }
  }
  if (h1) {
    float y0 = a10 * s, y1 = a11 * s, y2 = a12 * s;
    float* o = out + (long)b * SBo + (long)ch1 * 3 * NP + n;
    o[0] = y0; o[NP] = y1; o[2 * NP] = y2;
    int col = c0 + ch1;
    long r0 = ((long)b * 6144 + n) * 192 + col;
    float yv[3] = {y0, y1, y2};
#pragma unroll
    for (int d = 0; d < 3; ++d) {
      u16 h = f2bf(yv[d]);
      xth[r0 + (long)d * 2048 * 192] = h;
      xtl[r0 + (long)d * 2048 * 192] = f2bf(yv[d] - bf2f(h));
    }
  }
}

// ---------------- zero-pad xcatT cols 169..191 -----------------------------
__global__ __launch_bounds__(256) void k_padT(u16* __restrict__ Xh, u16* __restrict__ Xl) {
  int e = blockIdx.x * 256 + threadIdx.x;
  if (e >= 49152 * 23) return;
  int row = e / 23, col = 169 + e % 23;
  Xh[(long)row * 192 + col] = 0;
  Xl[(long)row * 192 + col] = 0;
}

// ---------------- qbuf[b][d][n] = sum_ci D5[ci] xcat[b][ci][d][n] ----------
__global__ __launch_bounds__(256) void k_qd5(const float* __restrict__ xcat,
                                             const float* __restrict__ D5,
                                             float* __restrict__ qbuf) {
  int e = blockIdx.x * 256 + threadIdx.x;
  if (e >= NB * 3 * NP) return;
  int n = e & 2047;
  int rest = e >> 11;
  int d = rest % 3, b = rest / 3;
  float s = 0.f;
  for (int ci = 0; ci < 169; ++ci)
    s += D5[ci] * xcat[(((long)b * 169 + ci) * 3 + d) * 2048 + n];
  qbuf[e] = s;
}

// ---------------- mean-half bias: one wave per (b,co,d) dot ----------------
__global__ __launch_bounds__(256) void k_bias(const float* __restrict__ Wfull,
                                              const float* __restrict__ x5m,
                                              float* __restrict__ outb) {
  int w = threadIdx.x >> 6, lane = threadIdx.x & 63;
  int p = blockIdx.x * 4 + w;
  int b = p / 1152, rem = p % 1152;
  int co = rem / 3, d = rem % 3;
  float s = 0.f;
  if (co < 341) {
    for (int mc = lane; mc < 341; mc += 64)
      s += Wfull[(long)co * 682 + 341 + mc] * x5m[((long)b * 341 + mc) * 3 + d];
  }
  for (int off = 32; off >= 1; off >>= 1) s += __shfl_xor(s, off);
  if (lane == 0) outb[((long)b * 384 + co) * 3 + d] = s;
}

// ---------------- split-bf16 MFMA VN-linear + VN-LeakyReLU (no LDS) --------
template <int HAS_D, int HAS_BIAS, int WF32, int WT>
__global__ __launch_bounds__(256) void k_vnmfma(
    const u16* __restrict__ Ah, const u16* __restrict__ Al, const u16* __restrict__ Dh,
    const u16* __restrict__ Dl, const u16* __restrict__ Bh, const u16* __restrict__ Bl,
    int KP, const float* __restrict__ qbuf, const float* __restrict__ biasP,
    const float* __restrict__ biasQ, int Co, float* __restrict__ Yf, u16* __restrict__ Yth,
    u16* __restrict__ Ytl, int COPn) {
  int tid = threadIdx.x, l = tid & 63, w = tid >> 6;
  int wm = w >> 1, wn = w & 1;
  int n0 = blockIdx.x * 64, co0 = blockIdx.y * 64, b = blockIdx.z;
  int lr = l & 15, lq = l >> 4, lk = lq * 8;
  f32x4 accP[2][2][3], accQ[2][2][3];
  f32x4 zz = {0.f, 0.f, 0.f, 0.f};
#pragma unroll
  for (int m = 0; m < 2; ++m)
#pragma unroll
    for (int ng = 0; ng < 2; ++ng)
#pragma unroll
      for (int d = 0; d < 3; ++d) { accP[m][ng][d] = zz; accQ[m][ng][d] = zz; }
  long arow0 = (long)(co0 + wm * 32 + lr) * KP + lk;
  long brow0 = ((long)b * 6144 + n0 + wn * 32 + lr) * KP + lk;
  const long dstr = 2048L * KP, ngstr = 16L * KP;
  for (int dc = 0; dc < KP; dc += 32) {
    bfx8 aWh[2], aWl[2], aDh[2], aDl[2];
#pragma unroll
    for (int m = 0; m < 2; ++m) {
      long arow = arow0 + (long)m * ngstr + dc;
      aWh[m] = *(const bfx8*)(Ah + arow);
      aWl[m] = *(const bfx8*)(Al + arow);
      if (HAS_D) {
        aDh[m] = *(const bfx8*)(Dh + arow);
        aDl[m] = *(const bfx8*)(Dl + arow);
      }
    }
    bfx8 bh[2][3], bl[2][3];
#pragma unroll
    for (int ng = 0; ng < 2; ++ng)
#pragma unroll
      for (int d = 0; d < 3; ++d) {
        long brow = brow0 + (long)ng * ngstr + (long)d * dstr + dc;
        bh[ng][d] = *(const bfx8*)(Bh + brow);
        bl[ng][d] = *(const bfx8*)(Bl + brow);
      }
#pragma unroll
    for (int m = 0; m < 2; ++m)
#pragma unroll
      for (int ng = 0; ng < 2; ++ng)
#pragma unroll
        for (int d = 0; d < 3; ++d) {
          accP[m][ng][d] =
              __builtin_amdgcn_mfma_f32_16x16x32_bf16(aWh[m], bh[ng][d], accP[m][ng][d], 0, 0, 0);
          accP[m][ng][d] =
              __builtin_amdgcn_mfma_f32_16x16x32_bf16(aWh[m], bl[ng][d], accP[m][ng][d], 0, 0, 0);
          accP[m][ng][d] =
              __builtin_amdgcn_mfma_f32_16x16x32_bf16(aWl[m], bh[ng][d], accP[m][ng][d], 0, 0, 0);
          if (HAS_D) {
            accQ[m][ng][d] = __builtin_amdgcn_mfma_f32_16x16x32_bf16(aDh[m], bh[ng][d],
                                                                     accQ[m][ng][d], 0, 0, 0);
            accQ[m][ng][d] = __builtin_amdgcn_mfma_f32_16x16x32_bf16(aDh[m], bl[ng][d],
                                                                     accQ[m][ng][d], 0, 0, 0);
            accQ[m][ng][d] = __builtin_amdgcn_mfma_f32_16x16x32_bf16(aDl[m], bh[ng][d],
                                                                     accQ[m][ng][d], 0, 0, 0);
          }
        }
  }
#pragma unroll
  for (int m = 0; m < 2; ++m) {
    int cob = co0 + wm * 32 + m * 16 + lq * 4;
#pragma unroll
    for (int ng = 0; ng < 2; ++ng) {
      int n = n0 + wn * 32 + ng * 16 + lr;
      float qd0 = 0.f, qd1 = 0.f, qd2 = 0.f;
      if (!HAS_D) {
        qd0 = qbuf[((long)b * 3 + 0) * 2048 + n];
        qd1 = qbuf[((long)b * 3 + 1) * 2048 + n];
        qd2 = qbuf[((long)b * 3 + 2) * 2048 + n];
      }
      float yv[3][4];
#pragma unroll
      for (int r = 0; r < 4; ++r) {
        int co = cob + r;
        float p0 = accP[m][ng][0][r], p1 = accP[m][ng][1][r], p2 = accP[m][ng][2][r];
        float q0, q1, q2;
        if (HAS_D) {
          q0 = accQ[m][ng][0][r]; q1 = accQ[m][ng][1][r]; q2 = accQ[m][ng][2][r];
        } else {
          q0 = qd0; q1 = qd1; q2 = qd2;
        }
        if (HAS_BIAS) {
          const float* bp = biasP + ((long)b * 384 + co) * 3;
          p0 += bp[0]; p1 += bp[1]; p2 += bp[2];
          const float* bq = biasQ + ((long)b * 384 + co) * 3;
          q0 += bq[0]; q1 += bq[1]; q2 += bq[2];
        }
        float dot = p0 * q0 + p1 * q1 + p2 * q2;
        float dsq = q0 * q0 + q1 * q1 + q2 * q2;
        float coef = dot < 0.f ? 0.8f * dot / (dsq + EPSF) : 0.f;
        yv[0][r] = p0 - coef * q0;
        yv[1][r] = p1 - coef * q1;
        yv[2][r] = p2 - coef * q2;
        if (WF32 && co < Co) {
          float* yb = Yf + ((long)b * Co + co) * 6144 + n;
          yb[0] = yv[0][r];
          yb[2048] = yv[1][r];
          yb[4096] = yv[2][r];
        }
      }
      if (WT && cob < COPn) {
#pragma unroll
        for (int d = 0; d < 3; ++d) {
          u16 hh[4], ll[4];
#pragma unroll
          for (int r = 0; r < 4; ++r) {
            hh[r] = f2bf(yv[d][r]);
            ll[r] = f2bf(yv[d][r] - bf2f(hh[r]));
          }
          long rowa = ((long)b * 6144 + d * 2048 + n) * COPn + cob;
          uint2 vh, vl2;
          vh.x = (unsigned)hh[0] | ((unsigned)hh[1] << 16);
          vh.y = (unsigned)hh[2] | ((unsigned)hh[3] << 16);
          vl2.x = (unsigned)ll[0] | ((unsigned)ll[1] << 16);
          vl2.y = (unsigned)ll[2] | ((unsigned)ll[3] << 16);
          *(uint2*)(Yth + rowa) = vh;
          *(uint2*)(Ytl + rowa) = vl2;
        }
      }
    }
  }
}

// ---------------- row means of x5 ------------------------------------------
__global__ __launch_bounds__(256) void k_mean(const float* __restrict__ X,
                                              float* __restrict__ M) {
  long row = blockIdx.x;
  const float* xr = X + row * (long)NP;
  float s = 0.f;
  for (int n = threadIdx.x; n < NP; n += 256) s += xr[n];
  __shared__ float red[256];
  red[threadIdx.x] = s;
  __syncthreads();
  for (int st = 128; st > 0; st >>= 1) {
    if (threadIdx.x < st) red[threadIdx.x] += red[threadIdx.x + st];
    __syncthreads();
  }
  if (threadIdx.x == 0) M[row] = red[0] * (1.f / NP);
}

// ---------------- final fold + lrelu + mean ---------------------------------
__global__ __launch_bounds__(256) void k_final(const float* __restrict__ x5,
                                               const float* __restrict__ x5m,
                                               const float* __restrict__ z2,
                                               const float* __restrict__ Wlin,
                                               const float* __restrict__ W6,
                                               const float* __restrict__ D6,
                                               float* __restrict__ part) {
  int b = blockIdx.x >> 5;
  int chunk = blockIdx.x & 31;
  int w = threadIdx.x >> 6, lane = threadIdx.x & 63;
  int n = chunk * 64 + lane;
  __shared__ float W6s[3 * 682];
  __shared__ float D6s[682];
  __shared__ float Wls[3 * 170];
  __shared__ float red[4][64][22];
  for (int e = threadIdx.x; e < 3 * 682; e += 256) W6s[e] = W6[e];
  for (int e = threadIdx.x; e < 682; e += 256) D6s[e] = D6[e];
  for (int e = threadIdx.x; e < 3 * 170; e += 256) Wls[e] = Wlin[e];
  __syncthreads();
  const float* x5b = x5 + (long)b * 341 * 3 * NP;
  const float* z2b = z2 + (long)b * 170 * 3 * NP;
  const float* mb = x5m + (long)b * 341 * 3;
  float G[9] = {0, 0, 0, 0, 0, 0, 0, 0, 0};
  float H[3] = {0, 0, 0};
  float Z[9] = {0, 0, 0, 0, 0, 0, 0, 0, 0};
  int i0 = w * 171, i1 = min(682, i0 + 171);
  for (int i = i0; i < i1; ++i) {
    float v0, v1, v2;
    if (i < 341) {
      const float* p = x5b + (long)i * 3 * NP + n;
      v0 = p[0]; v1 = p[NP]; v2 = p[2 * NP];
    } else {
      const float* p = mb + (i - 341) * 3;
      v0 = p[0]; v1 = p[1]; v2 = p[2];
    }
    float w0 = W6s[i], w1 = W6s[682 + i], w2 = W6s[2 * 682 + i];
    G[0] += w0 * v0; G[1] += w0 * v1; G[2] += w0 * v2;
    G[3] += w1 * v0; G[4] += w1 * v1; G[5] += w1 * v2;
    G[6] += w2 * v0; G[7] += w2 * v1; G[8] += w2 * v2;
    float wd = D6s[i];
    H[0] += wd * v0; H[1] += wd * v1; H[2] += wd * v2;
  }
  int c0 = w * 43, c1 = min(170, c0 + 43);
  for (int c = c0; c < c1; ++c) {
    const float* p = z2b + (long)c * 3 * NP + n;
    float u0 = p[0], u1 = p[NP], u2 = p[2 * NP];
    float w0 = Wls[c], w1 = Wls[170 + c], w2 = Wls[2 * 170 + c];
    Z[0] += w0 * u0; Z[3] += w0 * u1; Z[6] += w0 * u2;
    Z[1] += w1 * u0; Z[4] += w1 * u1; Z[7] += w1 * u2;
    Z[2] += w2 * u0; Z[5] += w2 * u1; Z[8] += w2 * u2;
  }
  float* rp = red[w][lane];
#pragma unroll
  for (int q = 0; q < 9; ++q) rp[q] = G[q];
#pragma unroll
  for (int q = 0; q < 3; ++q) rp[9 + q] = H[q];
#pragma unroll
  for (int q = 0; q < 9; ++q) rp[12 + q] = Z[q];
  __syncthreads();
  if (w == 0) {
#pragma unroll
    for (int q = 0; q < 9; ++q) G[q] += red[1][lane][q] + red[2][lane][q] + red[3][lane][q];
#pragma unroll
    for (int q = 0; q < 3; ++q)
      H[q] += red[1][lane][9 + q] + red[2][lane][9 + q] + red[3][lane][9 + q];
#pragma unroll
    for (int q = 0; q < 9; ++q)
      Z[q] += red[1][lane][12 + q] + red[2][lane][12 + q] + red[3][lane][12 + q];
    float dv0 = H[0] * Z[0] + H[1] * Z[3] + H[2] * Z[6];
    float dv1 = H[0] * Z[1] + H[1] * Z[4] + H[2] * Z[7];
    float dv2 = H[0] * Z[2] + H[1] * Z[5] + H[2] * Z[8];
    float dsq = dv0 * dv0 + dv1 * dv1 + dv2 * dv2;
    float res[9];
#pragma unroll
    for (int o = 0; o < 3; ++o) {
      float p0 = G[o * 3 + 0] * Z[0] + G[o * 3 + 1] * Z[3] + G[o * 3 + 2] * Z[6];
      float p1 = G[o * 3 + 0] * Z[1] + G[o * 3 + 1] * Z[4] + G[o * 3 + 2] * Z[7];
      float p2 = G[o * 3 + 0] * Z[2] + G[o * 3 + 1] * Z[5] + G[o * 3 + 2] * Z[8];
      float dot = p0 * dv0 + p1 * dv1 + p2 * dv2;
      float coef = dot < 0.f ? 0.8f * dot / (dsq + EPSF) : 0.f;
      res[o * 3 + 0] = p0 - coef * dv0;
      res[o * 3 + 1] = p1 - coef * dv1;
      res[o * 3 + 2] = p2 - coef * dv2;
    }
#pragma unroll
    for (int e = 0; e < 9; ++e) {
      float v = res[e];
      for (int off = 32; off >= 1; off >>= 1) v += __shfl_down(v, off);
      if (lane == 0) part[(long)blockIdx.x * 9 + e] = v;
    }
  }
}

__global__ __launch_bounds__(128) void k_reduce(const float* __restrict__ part,
                                                float* __restrict__ out) {
  int e = threadIdx.x;
  if (e < NB * 9) {
    int b = e / 9, r = e - b * 9;
    float s = 0.f;
    for (int c = 0; c < 32; ++c) s += part[((long)b * 32 + c) * 9 + r];
    out[e] = s * (1.f / NP);
  }
}

// ---------------------------------------------------------------------------
extern "C" void kernel_launch(void* const* d_in, const int* in_sizes, int n_in,
                              void* d_out, int out_size, void* d_ws, size_t ws_size,
                              hipStream_t stream) {
  (void)in_sizes; (void)n_in; (void)out_size;
  const float* x = (const float*)d_in[0];
  const float* W1 = (const float*)d_in[1];
  const float* D1 = (const float*)d_in[2];
  const float* W2 = (const float*)d_in[3];
  const float* D2 = (const float*)d_in[4];
  const float* W3 = (const float*)d_in[5];
  const float* D3w = (const float*)d_in[6];
  const float* W4 = (const float*)d_in[7];
  const float* D4 = (const float*)d_in[8];
  const float* W5 = (const float*)d_in[9];
  const float* D5 = (const float*)d_in[10];
  const float* Ws1 = (const float*)d_in[11];
  const float* Ds1 = (const float*)d_in[12];
  const float* Ws2 = (const float*)d_in[13];
  const float* Ds2 = (const float*)d_in[14];
  const float* Wlin = (const float*)d_in[15];
  const float* W6 = (const float*)d_in[16];
  const float* D6 = (const float*)d_in[17];

  // ---- workspace layout (float units) ----
  const long o_xT = 0;
  const long o_sq = 49152;
  const long o_idx = 65536;
  const long o_wcat = 393216;
  const long o_x5m = 532480;
  const long o_qbuf = 540672;
  const long o_biasP = 589824;
  const long o_biasQ = 599040;
  const long o_W5h = 608256;
  const long o_W5l = 645120;
  const long o_Ws1h = 681984;
  const long o_Ws1l = 749568;
  const long o_Ds1h = 817152;
  const long o_Ds1l = 884736;
  const long o_Ws2h = 952320;
  const long o_Ws2l = 986112;
  const long o_Ds2h = 1019904;
  const long o_Ds2l = 1053696;
  const long o_xcat = 1090560;
  const long o_xcTh = 9397248;
  const long o_xcTl = 14115840;
  const long o_nd = 18834432;
  const long o_x5Th = 35595264;
  const long o_x5Tl = 44246016;
  const long o_z1Th = 1090560;
  const long o_z1Tl = 9741312;
  const long o_z2 = 35595264;
  const long total_floats = 52896768;  // ~212 MB
  if (ws_size < (size_t)total_floats * 4) return;

  float* ws = (float*)d_ws;
  float* xT = ws + o_xT;
  float* sq = ws + o_sq;
  int* idx = (int*)(ws + o_idx);
  float* wc1 = ws + o_wcat;
  float* wc2 = ws + o_wcat + 128;
  float* wc3 = ws + o_wcat + 2048;
  float* wc4 = ws + o_wcat + 5632;
  float* part = ws + o_wcat;  // alias: wcatT dead after layer loop
  float* x5m = ws + o_x5m;
  float* qbuf = ws + o_qbuf;
  float* biasP = ws + o_biasP;
  float* biasQ = ws + o_biasQ;
  float* xcat = ws + o_xcat;
  float* nd = ws + o_nd;
  float* Ubuf = ws + o_nd;
  float* x5 = ws + o_nd;
  u16* xcTh = (u16*)(ws + o_xcTh);
  u16* xcTl = (u16*)(ws + o_xcTl);
  u16* x5Th = (u16*)(ws + o_x5Th);
  u16* x5Tl = (u16*)(ws + o_x5Tl);
  u16* z1Th = (u16*)(ws + o_z1Th);
  u16* z1Tl = (u16*)(ws + o_z1Tl);
  float* z2 = ws + o_z2;
  u16* W5h = (u16*)(ws + o_W5h);
  u16* W5l = (u16*)(ws + o_W5l);
  u16* Ws1h = (u16*)(ws + o_Ws1h);
  u16* Ws1l = (u16*)(ws + o_Ws1l);
  u16* Ds1h = (u16*)(ws + o_Ds1h);
  u16* Ds1l = (u16*)(ws + o_Ds1l);
  u16* Ws2h = (u16*)(ws + o_Ws2h);
  u16* Ws2l = (u16*)(ws + o_Ws2l);
  u16* Ds2h = (u16*)(ws + o_Ds2h);
  u16* Ds2l = (u16*)(ws + o_Ds2l);

  const long SBcat = 169L * 3 * NP;

  k_prep<<<(int)((SZ_PREP + 255) / 256), 256, 0, stream>>>(
      x, xT, W5, Ws1, Ds1, Ws2, Ds2, W5h, W5l, Ws1h, Ws1l, Ds1h, Ds1l, Ws2h, Ws2l, Ds2h, Ds2l,
      W1, D1, W2, D2, W3, D3w, W4, D4, wc1, wc2, wc3, wc4);
  k_padT<<<(49152 * 23 + 255) / 256, 256, 0, stream>>>(xcTh, xcTl);

  const float* Xl[4] = {xT, xcat, xcat + 21L * 3 * NP, xcat + 42L * 3 * NP};
  long SBl[4] = {3L * NP, SBcat, SBcat, SBcat};
  int Cl[4] = {1, 21, 21, 42};
  int Col[4] = {21, 21, 42, 85};
  int c0l[4] = {0, 21, 42, 84};
  float* wcl[4] = {wc1, wc2, wc3, wc4};

  for (int l = 0; l < 4; ++l) {
    int C = Cl[l], Co = Col[l], R4 = 4 * Co, Dd3 = 3 * C;
    k_sqnorm<<<NB * NP / 256, 256, 0, stream>>>(Xl[l], SBl[l], Dd3, sq);
    k_knn3<<<dim3(NP / 128, NP / 128, NB), 256, 0, stream>>>(Xl[l], SBl[l], Dd3, sq, nd);
    k_topk4<<<NB * NP / 4, 256, 0, stream>>>(nd, idx);
    k_gemm_u2<<<NB * NP / 64, 256, (size_t)C * 3 * 64 * 4, stream>>>(Xl[l], SBl[l], C, wcl[l],
                                                                     R4, Ubuf);
    k_edge<<<NB * NP / 4, 256, 0, stream>>>(Ubuf, R4, Co, idx, xcat + (long)c0l[l] * 3 * NP,
                                            SBcat, xcTh, xcTl, c0l[l]);
  }

  k_qd5<<<(NB * 3 * NP + 255) / 256, 256, 0, stream>>>(xcat, D5, qbuf);
  k_vnmfma<0, 0, 1, 1><<<dim3(32, 6, NB), 256, 0, stream>>>(
      W5h, W5l, nullptr, nullptr, xcTh, xcTl, 192, qbuf, nullptr, nullptr, 341, x5, x5Th, x5Tl,
      352);
  k_mean<<<NB * 341 * 3, 256, 0, stream>>>(x5, x5m);
  k_bias<<<NB * 1152 / 4, 256, 0, stream>>>(Ws1, x5m, biasP);
  k_bias<<<NB * 1152 / 4, 256, 0, stream>>>(Ds1, x5m, biasQ);
  k_vnmfma<1, 1, 0, 1><<<dim3(32, 6, NB), 256, 0, stream>>>(
      Ws1h, Ws1l, Ds1h, Ds1l, x5Th, x5Tl, 352, nullptr, biasP, biasQ, 341, nullptr, z1Th, z1Tl,
      352);
  k_vnmfma<1, 0, 1, 0><<<dim3(32, 3, NB), 256, 0, stream>>>(
      Ws2h, Ws2l, Ds2h, Ds2l, z1Th, z1Tl, 352, nullptr, nullptr, nullptr, 170, z2, nullptr,
      nullptr, 352);

  k_final<<<NB * 32, 256, 0, stream>>>(x5, x5m, z2, Wlin, W6, D6, part);
  k_reduce<<<1, 128, 0, stream>>>(part, (float*)d_out);
}

// Round 15
// 1212.328 us; speedup vs baseline: 1.1542x; 1.1542x over previous
//
#include <hip/hip_runtime.h>

#define NB 8
#define NP 2048
#define KNN 20
#define EPSF 1e-6f

typedef unsigned short u16;
typedef __bf16 bfx8 __attribute__((ext_vector_type(8)));
typedef float f32x4 __attribute__((ext_vector_type(4)));

__device__ __forceinline__ u16 f2bf(float x) {
  unsigned u = __float_as_uint(x);
  unsigned r = u + 0x7FFFu + ((u >> 16) & 1u);
  return (u16)(r >> 16);
}
__device__ __forceinline__ float bf2f(u16 h) { return __uint_as_float(((unsigned)h) << 16); }

// ---------------- fused prep: transpose + weight splits + wcatT ------------
__device__ __forceinline__ void wsplit_one(const float* __restrict__ W, int Co, int Cstride,
                                           int Ccopy, int KP, long e, u16* __restrict__ H,
                                           u16* __restrict__ L) {
  int r = (int)(e / KP), c = (int)(e - (long)r * KP);
  float v = (r < Co && c < Ccopy) ? W[(long)r * Cstride + c] : 0.f;
  u16 h = f2bf(v);
  H[e] = h;
  L[e] = f2bf(v - bf2f(h));
}
__device__ __forceinline__ void wcatT_one(const float* __restrict__ W,
                                          const float* __restrict__ Dm, int C, int Co, long e,
                                          float* __restrict__ WcT) {
  int R4 = 4 * Co;
  int c = (int)(e / R4);
  int rr = (int)(e - (long)c * R4);
  int g = rr / Co;
  int co = rr - g * Co;
  const float* M = (g < 2) ? W : Dm;
  long base = (long)co * 2 * C;
  WcT[e] = (g & 1) ? (M[base + C + c] - M[base + c]) : M[base + c];
}

#define SZ_XT 49152L
#define SZ_W5 73728L
#define SZ_WS1 135168L
#define SZ_WS2 67584L
#define SZ_WC1 84L
#define SZ_WC2 1764L
#define SZ_WC3 3528L
#define SZ_WC4 14280L
#define SZ_PREP (SZ_XT + SZ_W5 + 2 * SZ_WS1 + 2 * SZ_WS2 + SZ_WC1 + SZ_WC2 + SZ_WC3 + SZ_WC4)

__global__ __launch_bounds__(256) void k_prep(
    const float* __restrict__ x, float* __restrict__ xT, const float* __restrict__ W5,
    const float* __restrict__ Ws1, const float* __restrict__ Ds1,
    const float* __restrict__ Ws2, const float* __restrict__ Ds2, u16* __restrict__ W5h,
    u16* __restrict__ W5l, u16* __restrict__ Ws1h, u16* __restrict__ Ws1l,
    u16* __restrict__ Ds1h, u16* __restrict__ Ds1l, u16* __restrict__ Ws2h,
    u16* __restrict__ Ws2l, u16* __restrict__ Ds2h, u16* __restrict__ Ds2l,
    const float* __restrict__ W1, const float* __restrict__ D1, const float* __restrict__ W2,
    const float* __restrict__ D2, const float* __restrict__ W3, const float* __restrict__ D3w,
    const float* __restrict__ W4, const float* __restrict__ D4, float* __restrict__ wc1,
    float* __restrict__ wc2, float* __restrict__ wc3, float* __restrict__ wc4) {
  long e = (long)blockIdx.x * 256 + threadIdx.x;
  if (e < SZ_XT) {
    int n = (int)(e % NP);
    int r = (int)(e / NP);
    int d = r % 3, b = r / 3;
    xT[e] = x[((long)b * NP + n) * 3 + d];
    return;
  }
  e -= SZ_XT;
  if (e < SZ_W5) { wsplit_one(W5, 341, 169, 169, 192, e, W5h, W5l); return; }
  e -= SZ_W5;
  if (e < SZ_WS1) { wsplit_one(Ws1, 341, 682, 341, 352, e, Ws1h, Ws1l); return; }
  e -= SZ_WS1;
  if (e < SZ_WS1) { wsplit_one(Ds1, 341, 682, 341, 352, e, Ds1h, Ds1l); return; }
  e -= SZ_WS1;
  if (e < SZ_WS2) { wsplit_one(Ws2, 170, 341, 341, 352, e, Ws2h, Ws2l); return; }
  e -= SZ_WS2;
  if (e < SZ_WS2) { wsplit_one(Ds2, 170, 341, 341, 352, e, Ds2h, Ds2l); return; }
  e -= SZ_WS2;
  if (e < SZ_WC1) { wcatT_one(W1, D1, 1, 21, e, wc1); return; }
  e -= SZ_WC1;
  if (e < SZ_WC2) { wcatT_one(W2, D2, 21, 21, e, wc2); return; }
  e -= SZ_WC2;
  if (e < SZ_WC3) { wcatT_one(W3, D3w, 21, 42, e, wc3); return; }
  e -= SZ_WC3;
  if (e < SZ_WC4) { wcatT_one(W4, D4, 42, 85, e, wc4); return; }
}

// ---------------- row squared norms ---------------------------------------
__global__ __launch_bounds__(256) void k_sqnorm(const float* __restrict__ X, long SB, int D3,
                                                float* __restrict__ sq) {
  int e = blockIdx.x * 256 + threadIdx.x;
  int b = e >> 11, n = e & (NP - 1);
  const float* Xb = X + (long)b * SB + n;
  float s = 0.f;
  for (int d = 0; d < D3; ++d) {
    float v = Xb[(long)d * NP];
    s += v * v;
  }
  sq[e] = s;
}

// ---------------- pairwise neg sq distance: 128x128 tile, 8x8/thread -------
// (r13 version: unconditional zero-padded loads, single unrolled FMA loop)
__global__ __launch_bounds__(256) void k_knn3(const float* __restrict__ X, long SB, int D3,
                                              const float* __restrict__ sq,
                                              float* __restrict__ nd) {
  __shared__ float SI[32 * 128], SJ[32 * 128];
  int tid = threadIdx.x;
  int ti = tid & 15, tj = tid >> 4;
  int i0 = blockIdx.y * 128, j0 = blockIdx.x * 128, b = blockIdx.z;
  const float* Xb = X + (long)b * SB;
  float acc[8][8];
#pragma unroll
  for (int a = 0; a < 8; ++a)
#pragma unroll
    for (int c = 0; c < 8; ++c) acc[a][c] = 0.f;
  int qi0 = (2 * ti) ^ ((2 * ti) >> 2), qi1 = (2 * ti + 1) ^ ((2 * ti + 1) >> 2);
  int qj0 = (2 * tj) ^ ((2 * tj) >> 2), qj1 = (2 * tj + 1) ^ ((2 * tj + 1) >> 2);
  for (int dc = 0; dc < D3; dc += 32) {
    for (int e = tid; e < 1024; e += 256) {
      int q = e & 31, cc = e >> 5;
      int d = dc + cc;
      float4 vi, vj;
      if (d < D3) {
        vi = *(const float4*)(Xb + (long)d * NP + i0 + q * 4);
        vj = *(const float4*)(Xb + (long)d * NP + j0 + q * 4);
      } else {
        vi.x = vi.y = vi.z = vi.w = 0.f;
        vj = vi;
      }
      int qs = q ^ (q >> 2);
      *(float4*)&SI[cc * 128 + qs * 4] = vi;
      *(float4*)&SJ[cc * 128 + qs * 4] = vj;
    }
    __syncthreads();
    for (int cc = 0; cc < 32; ++cc) {
      float ir[8], jr[8];
      *(float4*)&ir[0] = *(const float4*)&SI[cc * 128 + qi0 * 4];
      *(float4*)&ir[4] = *(const float4*)&SI[cc * 128 + qi1 * 4];
      *(float4*)&jr[0] = *(const float4*)&SJ[cc * 128 + qj0 * 4];
      *(float4*)&jr[4] = *(const float4*)&SJ[cc * 128 + qj1 * 4];
#pragma unroll
      for (int a = 0; a < 8; ++a)
#pragma unroll
        for (int c = 0; c < 8; ++c) acc[a][c] += ir[a] * jr[c];
    }
    __syncthreads();
  }
  const float* sqb = sq + (long)b * NP;
  float sjr[8];
  *(float4*)&sjr[0] = *(const float4*)&sqb[j0 + tj * 8];
  *(float4*)&sjr[4] = *(const float4*)&sqb[j0 + tj * 8 + 4];
#pragma unroll
  for (int a = 0; a < 8; ++a) {
    int i = i0 + ti * 8 + a;
    float si = sqb[i];
    float o[8];
#pragma unroll
    for (int c = 0; c < 8; ++c) o[c] = 2.f * acc[a][c] - si - sjr[c];
    float* op = nd + ((long)b * NP + i) * NP + j0 + tj * 8;
    *(float4*)&op[0] = *(float4*)&o[0];
    *(float4*)&op[4] = *(float4*)&o[4];
  }
}

// ---------------- top-k (k=20): binary-search select + exact-count early exit
__global__ __launch_bounds__(256) void k_topk4(const float* __restrict__ nd,
                                               int* __restrict__ idx) {
  int wid = threadIdx.x >> 6, lane = threadIdx.x & 63;
  long row = (long)blockIdx.x * 4 + wid;
  const float4* r4 = (const float4*)(nd + row * NP);
  unsigned v[32];
#pragma unroll
  for (int m = 0; m < 8; ++m) {
    float4 w4 = r4[m * 64 + lane];
    float ww[4] = {w4.x, w4.y, w4.z, w4.w};
#pragma unroll
    for (int c = 0; c < 4; ++c) {
      unsigned b = __float_as_uint(ww[c]);
      v[m * 4 + c] = b ^ (unsigned)(((int)b >> 31) | 0x80000000);
    }
  }
  // find p: either count(v >= p) == KNN exactly (early exit; {v>=p} IS the
  // top-20 set), or p = V20 (largest p with count >= KNN) after full search.
  unsigned p = 0;
  for (int bit = 31; bit >= 0; --bit) {
    unsigned cand = p | (1u << bit);
    int cnt = 0;
#pragma unroll
    for (int e = 0; e < 32; ++e) cnt += (int)__popcll(__ballot(v[e] >= cand));
    if (cnt >= KNN) {
      p = cand;
      if (cnt == KNN) break;  // unique top-20 set identified
    }
  }
  int* op = idx + row * KNN;
  // emit strictly-greater (set semantics; order irrelevant downstream)
  int base = 0;
#pragma unroll
  for (int m = 0; m < 8; ++m) {
#pragma unroll
    for (int c = 0; c < 4; ++c) {
      int e = m * 4 + c;
      bool pr = v[e] > p;
      unsigned long long mk = __ballot(pr);
      if (pr) {
        int pos = base + (int)__popcll(mk & ((1ull << lane) - 1ull));
        op[pos] = m * 256 + lane * 4 + c;
      }
      base += (int)__popcll(mk);
    }
  }
  // ties: (KNN - base) lowest-index j with v == p
  int need = KNN - base;
  int tj[32];
#pragma unroll
  for (int m = 0; m < 8; ++m)
#pragma unroll
    for (int c = 0; c < 4; ++c) {
      int e = m * 4 + c;
      tj[e] = (v[e] == p) ? (m * 256 + lane * 4 + c) : (1 << 30);
    }
  int last = -1;
  while (need > 0) {
    int mn = 1 << 30;
#pragma unroll
    for (int e = 0; e < 32; ++e) {
      int t = tj[e];
      if (t > last && t < mn) mn = t;
    }
    for (int off = 32; off >= 1; off >>= 1) {
      int o = __shfl_xor(mn, off);
      if (o < mn) mn = o;
    }
    if (lane == 0) op[KNN - need] = mn;
    last = mn;
    --need;
  }
}

// ---------------- per-point GEMM (register-blocked): U[b][n][rr][d] --------
// 1-D grid; b = bid & 7 so each batch pins to one XCD (L2 affinity with edge).
__global__ __launch_bounds__(256) void k_gemm_u2(const float* __restrict__ X, long SB, int C,
                                                 const float* __restrict__ WcT, int R4,
                                                 float* __restrict__ U) {
  int bid = blockIdx.x;
  int b = bid & 7;
  int n0 = (bid >> 3) * 64;
  int tn = threadIdx.x & 15, tr = threadIdx.x >> 4;
  extern __shared__ float XS[];  // [3C][64]
  const float* Xb = X + (long)b * SB;
  int tot = 3 * C * 64;
  for (int e = threadIdx.x; e < tot; e += 256) {
    int nn = e & 63, rest = e >> 6;
    XS[e] = Xb[(long)rest * NP + n0 + nn];
  }
  __syncthreads();
  for (int rrb = tr * 4; rrb < R4; rrb += 64) {
    float acc[3][4][4];
#pragma unroll
    for (int d = 0; d < 3; ++d)
#pragma unroll
      for (int i = 0; i < 4; ++i)
#pragma unroll
        for (int j = 0; j < 4; ++j) acc[d][i][j] = 0.f;
    for (int c = 0; c < C; ++c) {
      float wv[4], x0[4], x1[4], x2[4];
      *(float4*)&wv[0] = *(const float4*)&WcT[(long)c * R4 + rrb];
      *(float4*)&x0[0] = *(const float4*)&XS[(c * 3 + 0) * 64 + tn * 4];
      *(float4*)&x1[0] = *(const float4*)&XS[(c * 3 + 1) * 64 + tn * 4];
      *(float4*)&x2[0] = *(const float4*)&XS[(c * 3 + 2) * 64 + tn * 4];
#pragma unroll
      for (int i = 0; i < 4; ++i) {
        float w = wv[i];
#pragma unroll
        for (int j = 0; j < 4; ++j) {
          acc[0][i][j] += w * x0[j];
          acc[1][i][j] += w * x1[j];
          acc[2][i][j] += w * x2[j];
        }
      }
    }
#pragma unroll
    for (int j = 0; j < 4; ++j) {
      float* Ub = U + (((long)b * NP + n0 + tn * 4 + j) * R4 + rrb) * 3;
#pragma unroll
      for (int i = 0; i < 4; ++i) {
        Ub[i * 3 + 0] = acc[0][i][j];
        Ub[i * 3 + 1] = acc[1][i][j];
        Ub[i * 3 + 2] = acc[2][i][j];
      }
    }
  }
}

// ---------------- edge aggregate (batch->XCD pinned) -----------------------
__global__ __launch_bounds__(256) void k_edge(const float* __restrict__ U, int R4, int Co,
                                              const int* __restrict__ idx,
                                              float* __restrict__ out, long SBo,
                                              u16* __restrict__ xth, u16* __restrict__ xtl,
                                              int c0) {
  int bid = blockIdx.x;
  int b = bid & 7;
  int n = (bid >> 3) * 4 + (threadIdx.x >> 6);
  int pt = b * NP + n;
  int lane = threadIdx.x & 63;
  const int* ip = idx + (long)pt * KNN;
  const float* Un = U + (long)pt * R4 * 3;
  int ch0 = lane, ch1 = lane + 64;
  bool h0 = ch0 < Co, h1 = ch1 < Co;
  float cp00 = 0, cp01 = 0, cp02 = 0, cd00 = 0, cd01 = 0, cd02 = 0;
  float cp10 = 0, cp11 = 0, cp12 = 0, cd10 = 0, cd11 = 0, cd12 = 0;
  if (h0) {
    cp00 = Un[(Co + ch0) * 3 + 0]; cp01 = Un[(Co + ch0) * 3 + 1]; cp02 = Un[(Co + ch0) * 3 + 2];
    cd00 = Un[(3 * Co + ch0) * 3 + 0]; cd01 = Un[(3 * Co + ch0) * 3 + 1]; cd02 = Un[(3 * Co + ch0) * 3 + 2];
  }
  if (h1) {
    cp10 = Un[(Co + ch1) * 3 + 0]; cp11 = Un[(Co + ch1) * 3 + 1]; cp12 = Un[(Co + ch1) * 3 + 2];
    cd10 = Un[(3 * Co + ch1) * 3 + 0]; cd11 = Un[(3 * Co + ch1) * 3 + 1]; cd12 = Un[(3 * Co + ch1) * 3 + 2];
  }
  float a00 = 0, a01 = 0, a02 = 0, a10 = 0, a11 = 0, a12 = 0;
  for (int kk = 0; kk < KNN; ++kk) {
    int j = ip[kk];
    const float* Uj = U + ((long)b * NP + j) * R4 * 3;
    if (h0) {
      float p0 = Uj[ch0 * 3 + 0] + cp00, p1 = Uj[ch0 * 3 + 1] + cp01, p2 = Uj[ch0 * 3 + 2] + cp02;
      float q0 = Uj[(2 * Co + ch0) * 3 + 0] + cd00, q1 = Uj[(2 * Co + ch0) * 3 + 1] + cd01,
            q2 = Uj[(2 * Co + ch0) * 3 + 2] + cd02;
      float dot = p0 * q0 + p1 * q1 + p2 * q2;
      float dsq = q0 * q0 + q1 * q1 + q2 * q2;
      float coef = dot < 0.f ? 0.8f * dot / (dsq + EPSF) : 0.f;
      a00 += p0 - coef * q0; a01 += p1 - coef * q1; a02 += p2 - coef * q2;
    }
    if (h1) {
      float p0 = Uj[ch1 * 3 + 0] + cp10, p1 = Uj[ch1 * 3 + 1] + cp11, p2 = Uj[ch1 * 3 + 2] + cp12;
      float q0 = Uj[(2 * Co + ch1) * 3 + 0] + cd10, q1 = Uj[(2 * Co + ch1) * 3 + 1] + cd11,
            q2 = Uj[(2 * Co + ch1) * 3 + 2] + cd12;
      float dot = p0 * q0 + p1 * q1 + p2 * q2;
      float dsq = q0 * q0 + q1 * q1 + q2 * q2;
      float coef = dot < 0.f ? 0.8f * dot / (dsq + EPSF) : 0.f;
      a10 += p0 - coef * q0; a11 += p1 - coef * q1; a12 += p2 - coef * q2;
    }
  }
  const float s = 1.f / KNN;
  if (h0) {
    float y0 = a00 * s, y1 = a01 * s, y2 = a02 * s;
    float* o = out + (long)b * SBo + (long)ch0 * 3 * NP + n;
    o[0] = y0; o[NP] = y1; o[2 * NP] = y2;
    int col = c0 + ch0;
    long r0 = ((long)b * 6144 + n) * 192 + col;
    float yv[3] = {y0, y1, y2};
#pragma unroll
    for (int d = 0; d < 3; ++d) {
      u16 h = f2bf(yv[d]);
      xth[r0 + (long)d * 2048 * 192] = h;
      xtl[r0 + (long)d * 2048 * 192] = f2bf(yv[d] - bf2f(h));
    }
  }
  if (h1) {
    float y0 = a10 * s, y1 = a11 * s, y2 = a12 * s;
    float* o = out + (long)b * SBo + (long)ch1 * 3 * NP + n;
    o[0] = y0; o[NP] = y1; o[2 * NP] = y2;
    int col = c0 + ch1;
    long r0 = ((long)b * 6144 + n) * 192 + col;
    float yv[3] = {y0, y1, y2};
#pragma unroll
    for (int d = 0; d < 3; ++d) {
      u16 h = f2bf(yv[d]);
      xth[r0 + (long)d * 2048 * 192] = h;
      xtl[r0 + (long)d * 2048 * 192] = f2bf(yv[d] - bf2f(h));
    }
  }
}

// ---------------- zero-pad xcatT cols 169..191 -----------------------------
__global__ __launch_bounds__(256) void k_padT(u16* __restrict__ Xh, u16* __restrict__ Xl) {
  int e = blockIdx.x * 256 + threadIdx.x;
  if (e >= 49152 * 23) return;
  int row = e / 23, col = 169 + e % 23;
  Xh[(long)row * 192 + col] = 0;
  Xl[(long)row * 192 + col] = 0;
}

// ---------------- qbuf[b][d][n] = sum_ci D5[ci] xcat[b][ci][d][n] ----------
__global__ __launch_bounds__(256) void k_qd5(const float* __restrict__ xcat,
                                             const float* __restrict__ D5,
                                             float* __restrict__ qbuf) {
  int e = blockIdx.x * 256 + threadIdx.x;
  if (e >= NB * 3 * NP) return;
  int n = e & 2047;
  int rest = e >> 11;
  int d = rest % 3, b = rest / 3;
  float s = 0.f;
  for (int ci = 0; ci < 169; ++ci)
    s += D5[ci] * xcat[(((long)b * 169 + ci) * 3 + d) * 2048 + n];
  qbuf[e] = s;
}

// ---------------- mean-half bias: one wave per (b,co,d) dot ----------------
__global__ __launch_bounds__(256) void k_bias(const float* __restrict__ Wfull,
                                              const float* __restrict__ x5m,
                                              float* __restrict__ outb) {
  int w = threadIdx.x >> 6, lane = threadIdx.x & 63;
  int p = blockIdx.x * 4 + w;
  int b = p / 1152, rem = p % 1152;
  int co = rem / 3, d = rem % 3;
  float s = 0.f;
  if (co < 341) {
    for (int mc = lane; mc < 341; mc += 64)
      s += Wfull[(long)co * 682 + 341 + mc] * x5m[((long)b * 341 + mc) * 3 + d];
  }
  for (int off = 32; off >= 1; off >>= 1) s += __shfl_xor(s, off);
  if (lane == 0) outb[((long)b * 384 + co) * 3 + d] = s;
}

// ---------------- split-bf16 MFMA VN-linear + VN-LeakyReLU (no LDS) --------
template <int HAS_D, int HAS_BIAS, int WF32, int WT>
__global__ __launch_bounds__(256) void k_vnmfma(
    const u16* __restrict__ Ah, const u16* __restrict__ Al, const u16* __restrict__ Dh,
    const u16* __restrict__ Dl, const u16* __restrict__ Bh, const u16* __restrict__ Bl,
    int KP, const float* __restrict__ qbuf, const float* __restrict__ biasP,
    const float* __restrict__ biasQ, int Co, float* __restrict__ Yf, u16* __restrict__ Yth,
    u16* __restrict__ Ytl, int COPn) {
  int tid = threadIdx.x, l = tid & 63, w = tid >> 6;
  int wm = w >> 1, wn = w & 1;
  int n0 = blockIdx.x * 64, co0 = blockIdx.y * 64, b = blockIdx.z;
  int lr = l & 15, lq = l >> 4, lk = lq * 8;
  f32x4 accP[2][2][3], accQ[2][2][3];
  f32x4 zz = {0.f, 0.f, 0.f, 0.f};
#pragma unroll
  for (int m = 0; m < 2; ++m)
#pragma unroll
    for (int ng = 0; ng < 2; ++ng)
#pragma unroll
      for (int d = 0; d < 3; ++d) { accP[m][ng][d] = zz; accQ[m][ng][d] = zz; }
  long arow0 = (long)(co0 + wm * 32 + lr) * KP + lk;
  long brow0 = ((long)b * 6144 + n0 + wn * 32 + lr) * KP + lk;
  const long dstr = 2048L * KP, ngstr = 16L * KP;
  for (int dc = 0; dc < KP; dc += 32) {
    bfx8 aWh[2], aWl[2], aDh[2], aDl[2];
#pragma unroll
    for (int m = 0; m < 2; ++m) {
      long arow = arow0 + (long)m * ngstr + dc;
      aWh[m] = *(const bfx8*)(Ah + arow);
      aWl[m] = *(const bfx8*)(Al + arow);
      if (HAS_D) {
        aDh[m] = *(const bfx8*)(Dh + arow);
        aDl[m] = *(const bfx8*)(Dl + arow);
      }
    }
    bfx8 bh[2][3], bl[2][3];
#pragma unroll
    for (int ng = 0; ng < 2; ++ng)
#pragma unroll
      for (int d = 0; d < 3; ++d) {
        long brow = brow0 + (long)ng * ngstr + (long)d * dstr + dc;
        bh[ng][d] = *(const bfx8*)(Bh + brow);
        bl[ng][d] = *(const bfx8*)(Bl + brow);
      }
#pragma unroll
    for (int m = 0; m < 2; ++m)
#pragma unroll
      for (int ng = 0; ng < 2; ++ng)
#pragma unroll
        for (int d = 0; d < 3; ++d) {
          accP[m][ng][d] =
              __builtin_amdgcn_mfma_f32_16x16x32_bf16(aWh[m], bh[ng][d], accP[m][ng][d], 0, 0, 0);
          accP[m][ng][d] =
              __builtin_amdgcn_mfma_f32_16x16x32_bf16(aWh[m], bl[ng][d], accP[m][ng][d], 0, 0, 0);
          accP[m][ng][d] =
              __builtin_amdgcn_mfma_f32_16x16x32_bf16(aWl[m], bh[ng][d], accP[m][ng][d], 0, 0, 0);
          if (HAS_D) {
            accQ[m][ng][d] = __builtin_amdgcn_mfma_f32_16x16x32_bf16(aDh[m], bh[ng][d],
                                                                     accQ[m][ng][d], 0, 0, 0);
            accQ[m][ng][d] = __builtin_amdgcn_mfma_f32_16x16x32_bf16(aDh[m], bl[ng][d],
                                                                     accQ[m][ng][d], 0, 0, 0);
            accQ[m][ng][d] = __builtin_amdgcn_mfma_f32_16x16x32_bf16(aDl[m], bh[ng][d],
                                                                     accQ[m][ng][d], 0, 0, 0);
          }
        }
  }
#pragma unroll
  for (int m = 0; m < 2; ++m) {
    int cob = co0 + wm * 32 + m * 16 + lq * 4;
#pragma unroll
    for (int ng = 0; ng < 2; ++ng) {
      int n = n0 + wn * 32 + ng * 16 + lr;
      float qd0 = 0.f, qd1 = 0.f, qd2 = 0.f;
      if (!HAS_D) {
        qd0 = qbuf[((long)b * 3 + 0) * 2048 + n];
        qd1 = qbuf[((long)b * 3 + 1) * 2048 + n];
        qd2 = qbuf[((long)b * 3 + 2) * 2048 + n];
      }
      float yv[3][4];
#pragma unroll
      for (int r = 0; r < 4; ++r) {
        int co = cob + r;
        float p0 = accP[m][ng][0][r], p1 = accP[m][ng][1][r], p2 = accP[m][ng][2][r];
        float q0, q1, q2;
        if (HAS_D) {
          q0 = accQ[m][ng][0][r]; q1 = accQ[m][ng][1][r]; q2 = accQ[m][ng][2][r];
        } else {
          q0 = qd0; q1 = qd1; q2 = qd2;
        }
        if (HAS_BIAS) {
          const float* bp = biasP + ((long)b * 384 + co) * 3;
          p0 += bp[0]; p1 += bp[1]; p2 += bp[2];
          const float* bq = biasQ + ((long)b * 384 + co) * 3;
          q0 += bq[0]; q1 += bq[1]; q2 += bq[2];
        }
        float dot = p0 * q0 + p1 * q1 + p2 * q2;
        float dsq = q0 * q0 + q1 * q1 + q2 * q2;
        float coef = dot < 0.f ? 0.8f * dot / (dsq + EPSF) : 0.f;
        yv[0][r] = p0 - coef * q0;
        yv[1][r] = p1 - coef * q1;
        yv[2][r] = p2 - coef * q2;
        if (WF32 && co < Co) {
          float* yb = Yf + ((long)b * Co + co) * 6144 + n;
          yb[0] = yv[0][r];
          yb[2048] = yv[1][r];
          yb[4096] = yv[2][r];
        }
      }
      if (WT && cob < COPn) {
#pragma unroll
        for (int d = 0; d < 3; ++d) {
          u16 hh[4], ll[4];
#pragma unroll
          for (int r = 0; r < 4; ++r) {
            hh[r] = f2bf(yv[d][r]);
            ll[r] = f2bf(yv[d][r] - bf2f(hh[r]));
          }
          long rowa = ((long)b * 6144 + d * 2048 + n) * COPn + cob;
          uint2 vh, vl2;
          vh.x = (unsigned)hh[0] | ((unsigned)hh[1] << 16);
          vh.y = (unsigned)hh[2] | ((unsigned)hh[3] << 16);
          vl2.x = (unsigned)ll[0] | ((unsigned)ll[1] << 16);
          vl2.y = (unsigned)ll[2] | ((unsigned)ll[3] << 16);
          *(uint2*)(Yth + rowa) = vh;
          *(uint2*)(Ytl + rowa) = vl2;
        }
      }
    }
  }
}

// ---------------- row means of x5 ------------------------------------------
__global__ __launch_bounds__(256) void k_mean(const float* __restrict__ X,
                                              float* __restrict__ M) {
  long row = blockIdx.x;
  const float* xr = X + row * (long)NP;
  float s = 0.f;
  for (int n = threadIdx.x; n < NP; n += 256) s += xr[n];
  __shared__ float red[256];
  red[threadIdx.x] = s;
  __syncthreads();
  for (int st = 128; st > 0; st >>= 1) {
    if (threadIdx.x < st) red[threadIdx.x] += red[threadIdx.x + st];
    __syncthreads();
  }
  if (threadIdx.x == 0) M[row] = red[0] * (1.f / NP);
}

// ---------------- final fold + lrelu + mean ---------------------------------
__global__ __launch_bounds__(256) void k_final(const float* __restrict__ x5,
                                               const float* __restrict__ x5m,
                                               const float* __restrict__ z2,
                                               const float* __restrict__ Wlin,
                                               const float* __restrict__ W6,
                                               const float* __restrict__ D6,
                                               float* __restrict__ part) {
  int b = blockIdx.x >> 5;
  int chunk = blockIdx.x & 31;
  int w = threadIdx.x >> 6, lane = threadIdx.x & 63;
  int n = chunk * 64 + lane;
  __shared__ float W6s[3 * 682];
  __shared__ float D6s[682];
  __shared__ float Wls[3 * 170];
  __shared__ float red[4][64][22];
  for (int e = threadIdx.x; e < 3 * 682; e += 256) W6s[e] = W6[e];
  for (int e = threadIdx.x; e < 682; e += 256) D6s[e] = D6[e];
  for (int e = threadIdx.x; e < 3 * 170; e += 256) Wls[e] = Wlin[e];
  __syncthreads();
  const float* x5b = x5 + (long)b * 341 * 3 * NP;
  const float* z2b = z2 + (long)b * 170 * 3 * NP;
  const float* mb = x5m + (long)b * 341 * 3;
  float G[9] = {0, 0, 0, 0, 0, 0, 0, 0, 0};
  float H[3] = {0, 0, 0};
  float Z[9] = {0, 0, 0, 0, 0, 0, 0, 0, 0};
  int i0 = w * 171, i1 = min(682, i0 + 171);
  for (int i = i0; i < i1; ++i) {
    float v0, v1, v2;
    if (i < 341) {
      const float* p = x5b + (long)i * 3 * NP + n;
      v0 = p[0]; v1 = p[NP]; v2 = p[2 * NP];
    } else {
      const float* p = mb + (i - 341) * 3;
      v0 = p[0]; v1 = p[1]; v2 = p[2];
    }
    float w0 = W6s[i], w1 = W6s[682 + i], w2 = W6s[2 * 682 + i];
    G[0] += w0 * v0; G[1] += w0 * v1; G[2] += w0 * v2;
    G[3] += w1 * v0; G[4] += w1 * v1; G[5] += w1 * v2;
    G[6] += w2 * v0; G[7] += w2 * v1; G[8] += w2 * v2;
    float wd = D6s[i];
    H[0] += wd * v0; H[1] += wd * v1; H[2] += wd * v2;
  }
  int c0 = w * 43, c1 = min(170, c0 + 43);
  for (int c = c0; c < c1; ++c) {
    const float* p = z2b + (long)c * 3 * NP + n;
    float u0 = p[0], u1 = p[NP], u2 = p[2 * NP];
    float w0 = Wls[c], w1 = Wls[170 + c], w2 = Wls[2 * 170 + c];
    Z[0] += w0 * u0; Z[3] += w0 * u1; Z[6] += w0 * u2;
    Z[1] += w1 * u0; Z[4] += w1 * u1; Z[7] += w1 * u2;
    Z[2] += w2 * u0; Z[5] += w2 * u1; Z[8] += w2 * u2;
  }
  float* rp = red[w][lane];
#pragma unroll
  for (int q = 0; q < 9; ++q) rp[q] = G[q];
#pragma unroll
  for (int q = 0; q < 3; ++q) rp[9 + q] = H[q];
#pragma unroll
  for (int q = 0; q < 9; ++q) rp[12 + q] = Z[q];
  __syncthreads();
  if (w == 0) {
#pragma unroll
    for (int q = 0; q < 9; ++q) G[q] += red[1][lane][q] + red[2][lane][q] + red[3][lane][q];
#pragma unroll
    for (int q = 0; q < 3; ++q)
      H[q] += red[1][lane][9 + q] + red[2][lane][9 + q] + red[3][lane][9 + q];
#pragma unroll
    for (int q = 0; q < 9; ++q)
      Z[q] += red[1][lane][12 + q] + red[2][lane][12 + q] + red[3][lane][12 + q];
    float dv0 = H[0] * Z[0] + H[1] * Z[3] + H[2] * Z[6];
    float dv1 = H[0] * Z[1] + H[1] * Z[4] + H[2] * Z[7];
    float dv2 = H[0] * Z[2] + H[1] * Z[5] + H[2] * Z[8];
    float dsq = dv0 * dv0 + dv1 * dv1 + dv2 * dv2;
    float res[9];
#pragma unroll
    for (int o = 0; o < 3; ++o) {
      float p0 = G[o * 3 + 0] * Z[0] + G[o * 3 + 1] * Z[3] + G[o * 3 + 2] * Z[6];
      float p1 = G[o * 3 + 0] * Z[1] + G[o * 3 + 1] * Z[4] + G[o * 3 + 2] * Z[7];
      float p2 = G[o * 3 + 0] * Z[2] + G[o * 3 + 1] * Z[5] + G[o * 3 + 2] * Z[8];
      float dot = p0 * dv0 + p1 * dv1 + p2 * dv2;
      float coef = dot < 0.f ? 0.8f * dot / (dsq + EPSF) : 0.f;
      res[o * 3 + 0] = p0 - coef * dv0;
      res[o * 3 + 1] = p1 - coef * dv1;
      res[o * 3 + 2] = p2 - coef * dv2;
    }
#pragma unroll
    for (int e = 0; e < 9; ++e) {
      float v = res[e];
      for (int off = 32; off >= 1; off >>= 1) v += __shfl_down(v, off);
      if (lane == 0) part[(long)blockIdx.x * 9 + e] = v;
    }
  }
}

__global__ __launch_bounds__(128) void k_reduce(const float* __restrict__ part,
                                                float* __restrict__ out) {
  int e = threadIdx.x;
  if (e < NB * 9) {
    int b = e / 9, r = e - b * 9;
    float s = 0.f;
    for (int c = 0; c < 32; ++c) s += part[((long)b * 32 + c) * 9 + r];
    out[e] = s * (1.f / NP);
  }
}

// ---------------------------------------------------------------------------
extern "C" void kernel_launch(void* const* d_in, const int* in_sizes, int n_in,
                              void* d_out, int out_size, void* d_ws, size_t ws_size,
                              hipStream_t stream) {
  (void)in_sizes; (void)n_in; (void)out_size;
  const float* x = (const float*)d_in[0];
  const float* W1 = (const float*)d_in[1];
  const float* D1 = (const float*)d_in[2];
  const float* W2 = (const float*)d_in[3];
  const float* D2 = (const float*)d_in[4];
  const float* W3 = (const float*)d_in[5];
  const float* D3w = (const float*)d_in[6];
  const float* W4 = (const float*)d_in[7];
  const float* D4 = (const float*)d_in[8];
  const float* W5 = (const float*)d_in[9];
  const float* D5 = (const float*)d_in[10];
  const float* Ws1 = (const float*)d_in[11];
  const float* Ds1 = (const float*)d_in[12];
  const float* Ws2 = (const float*)d_in[13];
  const float* Ds2 = (const float*)d_in[14];
  const float* Wlin = (const float*)d_in[15];
  const float* W6 = (const float*)d_in[16];
  const float* D6 = (const float*)d_in[17];

  // ---- workspace layout (float units) ----
  const long o_xT = 0;
  const long o_sq = 49152;
  const long o_idx = 65536;
  const long o_wcat = 393216;
  const long o_x5m = 532480;
  const long o_qbuf = 540672;
  const long o_biasP = 589824;
  const long o_biasQ = 599040;
  const long o_W5h = 608256;
  const long o_W5l = 645120;
  const long o_Ws1h = 681984;
  const long o_Ws1l = 749568;
  const long o_Ds1h = 817152;
  const long o_Ds1l = 884736;
  const long o_Ws2h = 952320;
  const long o_Ws2l = 986112;
  const long o_Ds2h = 1019904;
  const long o_Ds2l = 1053696;
  const long o_xcat = 1090560;
  const long o_xcTh = 9397248;
  const long o_xcTl = 14115840;
  const long o_nd = 18834432;
  const long o_x5Th = 35595264;
  const long o_x5Tl = 44246016;
  const long o_z1Th = 1090560;
  const long o_z1Tl = 9741312;
  const long o_z2 = 35595264;
  const long total_floats = 52896768;  // ~212 MB
  if (ws_size < (size_t)total_floats * 4) return;

  float* ws = (float*)d_ws;
  float* xT = ws + o_xT;
  float* sq = ws + o_sq;
  int* idx = (int*)(ws + o_idx);
  float* wc1 = ws + o_wcat;
  float* wc2 = ws + o_wcat + 128;
  float* wc3 = ws + o_wcat + 2048;
  float* wc4 = ws + o_wcat + 5632;
  float* part = ws + o_wcat;  // alias: wcatT dead after layer loop
  float* x5m = ws + o_x5m;
  float* qbuf = ws + o_qbuf;
  float* biasP = ws + o_biasP;
  float* biasQ = ws + o_biasQ;
  float* xcat = ws + o_xcat;
  float* nd = ws + o_nd;
  float* Ubuf = ws + o_nd;
  float* x5 = ws + o_nd;
  u16* xcTh = (u16*)(ws + o_xcTh);
  u16* xcTl = (u16*)(ws + o_xcTl);
  u16* x5Th = (u16*)(ws + o_x5Th);
  u16* x5Tl = (u16*)(ws + o_x5Tl);
  u16* z1Th = (u16*)(ws + o_z1Th);
  u16* z1Tl = (u16*)(ws + o_z1Tl);
  float* z2 = ws + o_z2;
  u16* W5h = (u16*)(ws + o_W5h);
  u16* W5l = (u16*)(ws + o_W5l);
  u16* Ws1h = (u16*)(ws + o_Ws1h);
  u16* Ws1l = (u16*)(ws + o_Ws1l);
  u16* Ds1h = (u16*)(ws + o_Ds1h);
  u16* Ds1l = (u16*)(ws + o_Ds1l);
  u16* Ws2h = (u16*)(ws + o_Ws2h);
  u16* Ws2l = (u16*)(ws + o_Ws2l);
  u16* Ds2h = (u16*)(ws + o_Ds2h);
  u16* Ds2l = (u16*)(ws + o_Ds2l);

  const long SBcat = 169L * 3 * NP;

  k_prep<<<(int)((SZ_PREP + 255) / 256), 256, 0, stream>>>(
      x, xT, W5, Ws1, Ds1, Ws2, Ds2, W5h, W5l, Ws1h, Ws1l, Ds1h, Ds1l, Ws2h, Ws2l, Ds2h, Ds2l,
      W1, D1, W2, D2, W3, D3w, W4, D4, wc1, wc2, wc3, wc4);
  k_padT<<<(49152 * 23 + 255) / 256, 256, 0, stream>>>(xcTh, xcTl);

  const float* Xl[4] = {xT, xcat, xcat + 21L * 3 * NP, xcat + 42L * 3 * NP};
  long SBl[4] = {3L * NP, SBcat, SBcat, SBcat};
  int Cl[4] = {1, 21, 21, 42};
  int Col[4] = {21, 21, 42, 85};
  int c0l[4] = {0, 21, 42, 84};
  float* wcl[4] = {wc1, wc2, wc3, wc4};

  for (int l = 0; l < 4; ++l) {
    int C = Cl[l], Co = Col[l], R4 = 4 * Co, Dd3 = 3 * C;
    k_sqnorm<<<NB * NP / 256, 256, 0, stream>>>(Xl[l], SBl[l], Dd3, sq);
    k_knn3<<<dim3(NP / 128, NP / 128, NB), 256, 0, stream>>>(Xl[l], SBl[l], Dd3, sq, nd);
    k_topk4<<<NB * NP / 4, 256, 0, stream>>>(nd, idx);
    k_gemm_u2<<<NB * NP / 64, 256, (size_t)C * 3 * 64 * 4, stream>>>(Xl[l], SBl[l], C, wcl[l],
                                                                     R4, Ubuf);
    k_edge<<<NB * NP / 4, 256, 0, stream>>>(Ubuf, R4, Co, idx, xcat + (long)c0l[l] * 3 * NP,
                                            SBcat, xcTh, xcTl, c0l[l]);
  }

  k_qd5<<<(NB * 3 * NP + 255) / 256, 256, 0, stream>>>(xcat, D5, qbuf);
  k_vnmfma<0, 0, 1, 1><<<dim3(32, 6, NB), 256, 0, stream>>>(
      W5h, W5l, nullptr, nullptr, xcTh, xcTl, 192, qbuf, nullptr, nullptr, 341, x5, x5Th, x5Tl,
      352);
  k_mean<<<NB * 341 * 3, 256, 0, stream>>>(x5, x5m);
  k_bias<<<NB * 1152 / 4, 256, 0, stream>>>(Ws1, x5m, biasP);
  k_bias<<<NB * 1152 / 4, 256, 0, stream>>>(Ds1, x5m, biasQ);
  k_vnmfma<1, 1, 0, 1><<<dim3(32, 6, NB), 256, 0, stream>>>(
      Ws1h, Ws1l, Ds1h, Ds1l, x5Th, x5Tl, 352, nullptr, biasP, biasQ, 341, nullptr, z1Th, z1Tl,
      352);
  k_vnmfma<1, 0, 1, 0><<<dim3(32, 3, NB), 256, 0, stream>>>(
      Ws2h, Ws2l, Ds2h, Ds2l, z1Th, z1Tl, 352, nullptr, nullptr, nullptr, 170, z2, nullptr,
      nullptr, 352);

  k_final<<<NB * 32, 256, 0, stream>>>(x5, x5m, z2, Wlin, W6, D6, part);
  k_reduce<<<1, 128, 0, stream>>>(part, (float*)d_out);
}

// Round 16
// 1193.817 us; speedup vs baseline: 1.1721x; 1.0155x over previous
//
#include <hip/hip_runtime.h>

#define NB 8
#define NP 2048
#define KNN 20
#define EPSF 1e-6f

typedef unsigned short u16;
typedef __bf16 bfx8 __attribute__((ext_vector_type(8)));
typedef float f32x4 __attribute__((ext_vector_type(4)));

__device__ __forceinline__ u16 f2bf(float x) {
  unsigned u = __float_as_uint(x);
  unsigned r = u + 0x7FFFu + ((u >> 16) & 1u);
  return (u16)(r >> 16);
}
__device__ __forceinline__ float bf2f(u16 h) { return __uint_as_float(((unsigned)h) << 16); }

// ---------------- fused prep: transpose + weight splits + wcatT + pad ------
__device__ __forceinline__ void wsplit_one(const float* __restrict__ W, int Co, int Cstride,
                                           int Ccopy, int KP, long e, u16* __restrict__ H,
                                           u16* __restrict__ L) {
  int r = (int)(e / KP), c = (int)(e - (long)r * KP);
  float v = (r < Co && c < Ccopy) ? W[(long)r * Cstride + c] : 0.f;
  u16 h = f2bf(v);
  H[e] = h;
  L[e] = f2bf(v - bf2f(h));
}
__device__ __forceinline__ void wcatT_one(const float* __restrict__ W,
                                          const float* __restrict__ Dm, int C, int Co, long e,
                                          float* __restrict__ WcT) {
  int R4 = 4 * Co;
  int c = (int)(e / R4);
  int rr = (int)(e - (long)c * R4);
  int g = rr / Co;
  int co = rr - g * Co;
  const float* M = (g < 2) ? W : Dm;
  long base = (long)co * 2 * C;
  WcT[e] = (g & 1) ? (M[base + C + c] - M[base + c]) : M[base + c];
}

#define SZ_XT 49152L
#define SZ_W5 73728L
#define SZ_WS1 135168L
#define SZ_WS2 67584L
#define SZ_WC1 84L
#define SZ_WC2 1764L
#define SZ_WC3 3528L
#define SZ_WC4 14280L
#define SZ_PAD 1130496L  // 49152 rows * 23 pad cols
#define SZ_PREP \
  (SZ_XT + SZ_W5 + 2 * SZ_WS1 + 2 * SZ_WS2 + SZ_WC1 + SZ_WC2 + SZ_WC3 + SZ_WC4 + SZ_PAD)

__global__ __launch_bounds__(256) void k_prep(
    const float* __restrict__ x, float* __restrict__ xT, const float* __restrict__ W5,
    const float* __restrict__ Ws1, const float* __restrict__ Ds1,
    const float* __restrict__ Ws2, const float* __restrict__ Ds2, u16* __restrict__ W5h,
    u16* __restrict__ W5l, u16* __restrict__ Ws1h, u16* __restrict__ Ws1l,
    u16* __restrict__ Ds1h, u16* __restrict__ Ds1l, u16* __restrict__ Ws2h,
    u16* __restrict__ Ws2l, u16* __restrict__ Ds2h, u16* __restrict__ Ds2l,
    const float* __restrict__ W1, const float* __restrict__ D1, const float* __restrict__ W2,
    const float* __restrict__ D2, const float* __restrict__ W3, const float* __restrict__ D3w,
    const float* __restrict__ W4, const float* __restrict__ D4, float* __restrict__ wc1,
    float* __restrict__ wc2, float* __restrict__ wc3, float* __restrict__ wc4,
    u16* __restrict__ Xh, u16* __restrict__ Xl) {
  long e = (long)blockIdx.x * 256 + threadIdx.x;
  if (e < SZ_XT) {
    int n = (int)(e % NP);
    int r = (int)(e / NP);
    int d = r % 3, b = r / 3;
    xT[e] = x[((long)b * NP + n) * 3 + d];
    return;
  }
  e -= SZ_XT;
  if (e < SZ_W5) { wsplit_one(W5, 341, 169, 169, 192, e, W5h, W5l); return; }
  e -= SZ_W5;
  if (e < SZ_WS1) { wsplit_one(Ws1, 341, 682, 341, 352, e, Ws1h, Ws1l); return; }
  e -= SZ_WS1;
  if (e < SZ_WS1) { wsplit_one(Ds1, 341, 682, 341, 352, e, Ds1h, Ds1l); return; }
  e -= SZ_WS1;
  if (e < SZ_WS2) { wsplit_one(Ws2, 170, 341, 341, 352, e, Ws2h, Ws2l); return; }
  e -= SZ_WS2;
  if (e < SZ_WS2) { wsplit_one(Ds2, 170, 341, 341, 352, e, Ds2h, Ds2l); return; }
  e -= SZ_WS2;
  if (e < SZ_WC1) { wcatT_one(W1, D1, 1, 21, e, wc1); return; }
  e -= SZ_WC1;
  if (e < SZ_WC2) { wcatT_one(W2, D2, 21, 21, e, wc2); return; }
  e -= SZ_WC2;
  if (e < SZ_WC3) { wcatT_one(W3, D3w, 21, 42, e, wc3); return; }
  e -= SZ_WC3;
  if (e < SZ_WC4) { wcatT_one(W4, D4, 42, 85, e, wc4); return; }
  e -= SZ_WC4;
  if (e < SZ_PAD) {
    long row = e / 23;
    int col = 169 + (int)(e % 23);
    Xh[row * 192 + col] = 0;
    Xl[row * 192 + col] = 0;
  }
}

// ---------------- row squared norms ---------------------------------------
__global__ __launch_bounds__(256) void k_sqnorm(const float* __restrict__ X, long SB, int D3,
                                                float* __restrict__ sq) {
  int e = blockIdx.x * 256 + threadIdx.x;
  int b = e >> 11, n = e & (NP - 1);
  const float* Xb = X + (long)b * SB + n;
  float s = 0.f;
  for (int d = 0; d < D3; ++d) {
    float v = Xb[(long)d * NP];
    s += v * v;
  }
  sq[e] = s;
}

// ---------------- pairwise neg sq distance: 128x128 tile, 8x8/thread -------
// Compile-time D3 (3 / 63 / 126): no padding waste, no runtime branches.
template <int D3>
__global__ __launch_bounds__(256) void k_knn3(const float* __restrict__ X, long SB,
                                              const float* __restrict__ sq,
                                              float* __restrict__ nd) {
  __shared__ float SI[32 * 128], SJ[32 * 128];
  int tid = threadIdx.x;
  int ti = tid & 15, tj = tid >> 4;
  int i0 = blockIdx.y * 128, j0 = blockIdx.x * 128, b = blockIdx.z;
  const float* Xb = X + (long)b * SB;
  float acc[8][8];
#pragma unroll
  for (int a = 0; a < 8; ++a)
#pragma unroll
    for (int c = 0; c < 8; ++c) acc[a][c] = 0.f;
  int qi0 = (2 * ti) ^ ((2 * ti) >> 2), qi1 = (2 * ti + 1) ^ ((2 * ti + 1) >> 2);
  int qj0 = (2 * tj) ^ ((2 * tj) >> 2), qj1 = (2 * tj + 1) ^ ((2 * tj + 1) >> 2);
#pragma unroll 1
  for (int dc = 0; dc < D3; dc += 32) {
    const int cend = (D3 - dc < 32) ? (D3 - dc) : 32;
    for (int e = tid; e < cend * 32; e += 256) {
      int q = e & 31, cc = e >> 5;
      int d = dc + cc;
      float4 vi = *(const float4*)(Xb + (long)d * NP + i0 + q * 4);
      float4 vj = *(const float4*)(Xb + (long)d * NP + j0 + q * 4);
      int qs = q ^ (q >> 2);
      *(float4*)&SI[cc * 128 + qs * 4] = vi;
      *(float4*)&SJ[cc * 128 + qs * 4] = vj;
    }
    __syncthreads();
#pragma unroll
    for (int cc = 0; cc < cend; ++cc) {
      float ir[8], jr[8];
      *(float4*)&ir[0] = *(const float4*)&SI[cc * 128 + qi0 * 4];
      *(float4*)&ir[4] = *(const float4*)&SI[cc * 128 + qi1 * 4];
      *(float4*)&jr[0] = *(const float4*)&SJ[cc * 128 + qj0 * 4];
      *(float4*)&jr[4] = *(const float4*)&SJ[cc * 128 + qj1 * 4];
#pragma unroll
      for (int a = 0; a < 8; ++a)
#pragma unroll
        for (int c = 0; c < 8; ++c) acc[a][c] += ir[a] * jr[c];
    }
    __syncthreads();
  }
  const float* sqb = sq + (long)b * NP;
  float sjr[8];
  *(float4*)&sjr[0] = *(const float4*)&sqb[j0 + tj * 8];
  *(float4*)&sjr[4] = *(const float4*)&sqb[j0 + tj * 8 + 4];
#pragma unroll
  for (int a = 0; a < 8; ++a) {
    int i = i0 + ti * 8 + a;
    float si = sqb[i];
    float o[8];
#pragma unroll
    for (int c = 0; c < 8; ++c) o[c] = 2.f * acc[a][c] - si - sjr[c];
    float* op = nd + ((long)b * NP + i) * NP + j0 + tj * 8;
    *(float4*)&op[0] = *(float4*)&o[0];
    *(float4*)&op[4] = *(float4*)&o[4];
  }
}

// ---------------- top-k (k=20): binary-search select + exact-count early exit
__global__ __launch_bounds__(256) void k_topk4(const float* __restrict__ nd,
                                               int* __restrict__ idx) {
  int wid = threadIdx.x >> 6, lane = threadIdx.x & 63;
  long row = (long)blockIdx.x * 4 + wid;
  const float4* r4 = (const float4*)(nd + row * NP);
  unsigned v[32];
#pragma unroll
  for (int m = 0; m < 8; ++m) {
    float4 w4 = r4[m * 64 + lane];
    float ww[4] = {w4.x, w4.y, w4.z, w4.w};
#pragma unroll
    for (int c = 0; c < 4; ++c) {
      unsigned b = __float_as_uint(ww[c]);
      v[m * 4 + c] = b ^ (unsigned)(((int)b >> 31) | 0x80000000);
    }
  }
  unsigned p = 0;
  for (int bit = 31; bit >= 0; --bit) {
    unsigned cand = p | (1u << bit);
    int cnt = 0;
#pragma unroll
    for (int e = 0; e < 32; ++e) cnt += (int)__popcll(__ballot(v[e] >= cand));
    if (cnt >= KNN) {
      p = cand;
      if (cnt == KNN) break;
    }
  }
  int* op = idx + row * KNN;
  int base = 0;
#pragma unroll
  for (int m = 0; m < 8; ++m) {
#pragma unroll
    for (int c = 0; c < 4; ++c) {
      int e = m * 4 + c;
      bool pr = v[e] > p;
      unsigned long long mk = __ballot(pr);
      if (pr) {
        int pos = base + (int)__popcll(mk & ((1ull << lane) - 1ull));
        op[pos] = m * 256 + lane * 4 + c;
      }
      base += (int)__popcll(mk);
    }
  }
  int need = KNN - base;
  int tj[32];
#pragma unroll
  for (int m = 0; m < 8; ++m)
#pragma unroll
    for (int c = 0; c < 4; ++c) {
      int e = m * 4 + c;
      tj[e] = (v[e] == p) ? (m * 256 + lane * 4 + c) : (1 << 30);
    }
  int last = -1;
  while (need > 0) {
    int mn = 1 << 30;
#pragma unroll
    for (int e = 0; e < 32; ++e) {
      int t = tj[e];
      if (t > last && t < mn) mn = t;
    }
    for (int off = 32; off >= 1; off >>= 1) {
      int o = __shfl_xor(mn, off);
      if (o < mn) mn = o;
    }
    if (lane == 0) op[KNN - need] = mn;
    last = mn;
    --need;
  }
}

// ---------------- per-point GEMM (register-blocked): U[b][n][rr][d] --------
__global__ __launch_bounds__(256) void k_gemm_u2(const float* __restrict__ X, long SB, int C,
                                                 const float* __restrict__ WcT, int R4,
                                                 float* __restrict__ U) {
  int bid = blockIdx.x;
  int b = bid & 7;
  int n0 = (bid >> 3) * 64;
  int tn = threadIdx.x & 15, tr = threadIdx.x >> 4;
  extern __shared__ float XS[];  // [3C][64]
  const float* Xb = X + (long)b * SB;
  int tot = 3 * C * 64;
  for (int e = threadIdx.x; e < tot; e += 256) {
    int nn = e & 63, rest = e >> 6;
    XS[e] = Xb[(long)rest * NP + n0 + nn];
  }
  __syncthreads();
  for (int rrb = tr * 4; rrb < R4; rrb += 64) {
    float acc[3][4][4];
#pragma unroll
    for (int d = 0; d < 3; ++d)
#pragma unroll
      for (int i = 0; i < 4; ++i)
#pragma unroll
        for (int j = 0; j < 4; ++j) acc[d][i][j] = 0.f;
    for (int c = 0; c < C; ++c) {
      float wv[4], x0[4], x1[4], x2[4];
      *(float4*)&wv[0] = *(const float4*)&WcT[(long)c * R4 + rrb];
      *(float4*)&x0[0] = *(const float4*)&XS[(c * 3 + 0) * 64 + tn * 4];
      *(float4*)&x1[0] = *(const float4*)&XS[(c * 3 + 1) * 64 + tn * 4];
      *(float4*)&x2[0] = *(const float4*)&XS[(c * 3 + 2) * 64 + tn * 4];
#pragma unroll
      for (int i = 0; i < 4; ++i) {
        float w = wv[i];
#pragma unroll
        for (int j = 0; j < 4; ++j) {
          acc[0][i][j] += w * x0[j];
          acc[1][i][j] += w * x1[j];
          acc[2][i][j] += w * x2[j];
        }
      }
    }
#pragma unroll
    for (int j = 0; j < 4; ++j) {
      float* Ub = U + (((long)b * NP + n0 + tn * 4 + j) * R4 + rrb) * 3;
#pragma unroll
      for (int i = 0; i < 4; ++i) {
        Ub[i * 3 + 0] = acc[0][i][j];
        Ub[i * 3 + 1] = acc[1][i][j];
        Ub[i * 3 + 2] = acc[2][i][j];
      }
    }
  }
}

// ---------------- edge aggregate (batch->XCD pinned) -----------------------
__global__ __launch_bounds__(256) void k_edge(const float* __restrict__ U, int R4, int Co,
                                              const int* __restrict__ idx,
                                              float* __restrict__ out, long SBo,
                                              u16* __restrict__ xth, u16* __restrict__ xtl,
                                              int c0) {
  int bid = blockIdx.x;
  int b = bid & 7;
  int n = (bid >> 3) * 4 + (threadIdx.x >> 6);
  int pt = b * NP + n;
  int lane = threadIdx.x & 63;
  const int* ip = idx + (long)pt * KNN;
  const float* Un = U + (long)pt * R4 * 3;
  int ch0 = lane, ch1 = lane + 64;
  bool h0 = ch0 < Co, h1 = ch1 < Co;
  float cp00 = 0, cp01 = 0, cp02 = 0, cd00 = 0, cd01 = 0, cd02 = 0;
  float cp10 = 0, cp11 = 0, cp12 = 0, cd10 = 0, cd11 = 0, cd12 = 0;
  if (h0) {
    cp00 = Un[(Co + ch0) * 3 + 0]; cp01 = Un[(Co + ch0) * 3 + 1]; cp02 = Un[(Co + ch0) * 3 + 2];
    cd00 = Un[(3 * Co + ch0) * 3 + 0]; cd01 = Un[(3 * Co + ch0) * 3 + 1]; cd02 = Un[(3 * Co + ch0) * 3 + 2];
  }
  if (h1) {
    cp10 = Un[(Co + ch1) * 3 + 0]; cp11 = Un[(Co + ch1) * 3 + 1]; cp12 = Un[(Co + ch1) * 3 + 2];
    cd10 = Un[(3 * Co + ch1) * 3 + 0]; cd11 = Un[(3 * Co + ch1) * 3 + 1]; cd12 = Un[(3 * Co + ch1) * 3 + 2];
  }
  float a00 = 0, a01 = 0, a02 = 0, a10 = 0, a11 = 0, a12 = 0;
  for (int kk = 0; kk < KNN; ++kk) {
    int j = ip[kk];
    const float* Uj = U + ((long)b * NP + j) * R4 * 3;
    if (h0) {
      float p0 = Uj[ch0 * 3 + 0] + cp00, p1 = Uj[ch0 * 3 + 1] + cp01, p2 = Uj[ch0 * 3 + 2] + cp02;
      float q0 = Uj[(2 * Co + ch0) * 3 + 0] + cd00, q1 = Uj[(2 * Co + ch0) * 3 + 1] + cd01,
            q2 = Uj[(2 * Co + ch0) * 3 + 2] + cd02;
      float dot = p0 * q0 + p1 * q1 + p2 * q2;
      float dsq = q0 * q0 + q1 * q1 + q2 * q2;
      float coef = dot < 0.f ? 0.8f * dot / (dsq + EPSF) : 0.f;
      a00 += p0 - coef * q0; a01 += p1 - coef * q1; a02 += p2 - coef * q2;
    }
    if (h1) {
      float p0 = Uj[ch1 * 3 + 0] + cp10, p1 = Uj[ch1 * 3 + 1] + cp11, p2 = Uj[ch1 * 3 + 2] + cp12;
      float q0 = Uj[(2 * Co + ch1) * 3 + 0] + cd10, q1 = Uj[(2 * Co + ch1) * 3 + 1] + cd11,
            q2 = Uj[(2 * Co + ch1) * 3 + 2] + cd12;
      float dot = p0 * q0 + p1 * q1 + p2 * q2;
      float dsq = q0 * q0 + q1 * q1 + q2 * q2;
      float coef = dot < 0.f ? 0.8f * dot / (dsq + EPSF) : 0.f;
      a10 += p0 - coef * q0; a11 += p1 - coef * q1; a12 += p2 - coef * q2;
    }
  }
  const float s = 1.f / KNN;
  if (h0) {
    float y0 = a00 * s, y1 = a01 * s, y2 = a02 * s;
    float* o = out + (long)b * SBo + (long)ch0 * 3 * NP + n;
    o[0] = y0; o[NP] = y1; o[2 * NP] = y2;
    int col = c0 + ch0;
    long r0 = ((long)b * 6144 + n) * 192 + col;
    float yv[3] = {y0, y1, y2};
#pragma unroll
    for (int d = 0; d < 3; ++d) {
      u16 h = f2bf(yv[d]);
      xth[r0 + (long)d * 2048 * 192] = h;
      xtl[r0 + (long)d * 2048 * 192] = f2bf(yv[d] - bf2f(h));
    }
  }
  if (h1) {
    float y0 = a10 * s, y1 = a11 * s, y2 = a12 * s;
    float* o = out + (long)b * SBo + (long)ch1 * 3 * NP + n;
    o[0] = y0; o[NP] = y1; o[2 * NP] = y2;
    int col = c0 + ch1;
    long r0 = ((long)b * 6144 + n) * 192 + col;
    float yv[3] = {y0, y1, y2};
#pragma unroll
    for (int d = 0; d < 3; ++d) {
      u16 h = f2bf(yv[d]);
      xth[r0 + (long)d * 2048 * 192] = h;
      xtl[r0 + (long)d * 2048 * 192] = f2bf(yv[d] - bf2f(h));
    }
  }
}

// ---------------- qbuf[b][d][n] = sum_ci D5[ci] xcat[b][ci][d][n] ----------
__global__ __launch_bounds__(256) void k_qd5(const float* __restrict__ xcat,
                                             const float* __restrict__ D5,
                                             float* __restrict__ qbuf) {
  int e = blockIdx.x * 256 + threadIdx.x;
  if (e >= NB * 3 * NP) return;
  int n = e & 2047;
  int rest = e >> 11;
  int d = rest % 3, b = rest / 3;
  float s = 0.f;
  for (int ci = 0; ci < 169; ++ci)
    s += D5[ci] * xcat[(((long)b * 169 + ci) * 3 + d) * 2048 + n];
  qbuf[e] = s;
}

// ---------------- mean-half bias: one wave per (b,co,d) dot ----------------
__global__ __launch_bounds__(256) void k_bias(const float* __restrict__ Wfull,
                                              const float* __restrict__ x5m,
                                              float* __restrict__ outb) {
  int w = threadIdx.x >> 6, lane = threadIdx.x & 63;
  int p = blockIdx.x * 4 + w;
  int b = p / 1152, rem = p % 1152;
  int co = rem / 3, d = rem % 3;
  float s = 0.f;
  if (co < 341) {
    for (int mc = lane; mc < 341; mc += 64)
      s += Wfull[(long)co * 682 + 341 + mc] * x5m[((long)b * 341 + mc) * 3 + d];
  }
  for (int off = 32; off >= 1; off >>= 1) s += __shfl_xor(s, off);
  if (lane == 0) outb[((long)b * 384 + co) * 3 + d] = s;
}

// ---------------- split-bf16 MFMA VN-linear + VN-LeakyReLU (no LDS) --------
template <int HAS_D, int HAS_BIAS, int WF32, int WT>
__global__ __launch_bounds__(256) void k_vnmfma(
    const u16* __restrict__ Ah, const u16* __restrict__ Al, const u16* __restrict__ Dh,
    const u16* __restrict__ Dl, const u16* __restrict__ Bh, const u16* __restrict__ Bl,
    int KP, const float* __restrict__ qbuf, const float* __restrict__ biasP,
    const float* __restrict__ biasQ, int Co, float* __restrict__ Yf, u16* __restrict__ Yth,
    u16* __restrict__ Ytl, int COPn) {
  int tid = threadIdx.x, l = tid & 63, w = tid >> 6;
  int wm = w >> 1, wn = w & 1;
  int n0 = blockIdx.x * 64, co0 = blockIdx.y * 64, b = blockIdx.z;
  int lr = l & 15, lq = l >> 4, lk = lq * 8;
  f32x4 accP[2][2][3], accQ[2][2][3];
  f32x4 zz = {0.f, 0.f, 0.f, 0.f};
#pragma unroll
  for (int m = 0; m < 2; ++m)
#pragma unroll
    for (int ng = 0; ng < 2; ++ng)
#pragma unroll
      for (int d = 0; d < 3; ++d) { accP[m][ng][d] = zz; accQ[m][ng][d] = zz; }
  long arow0 = (long)(co0 + wm * 32 + lr) * KP + lk;
  long brow0 = ((long)b * 6144 + n0 + wn * 32 + lr) * KP + lk;
  const long dstr = 2048L * KP, ngstr = 16L * KP;
  for (int dc = 0; dc < KP; dc += 32) {
    bfx8 aWh[2], aWl[2], aDh[2], aDl[2];
#pragma unroll
    for (int m = 0; m < 2; ++m) {
      long arow = arow0 + (long)m * ngstr + dc;
      aWh[m] = *(const bfx8*)(Ah + arow);
      aWl[m] = *(const bfx8*)(Al + arow);
      if (HAS_D) {
        aDh[m] = *(const bfx8*)(Dh + arow);
        aDl[m] = *(const bfx8*)(Dl + arow);
      }
    }
    bfx8 bh[2][3], bl[2][3];
#pragma unroll
    for (int ng = 0; ng < 2; ++ng)
#pragma unroll
      for (int d = 0; d < 3; ++d) {
        long brow = brow0 + (long)ng * ngstr + (long)d * dstr + dc;
        bh[ng][d] = *(const bfx8*)(Bh + brow);
        bl[ng][d] = *(const bfx8*)(Bl + brow);
      }
#pragma unroll
    for (int m = 0; m < 2; ++m)
#pragma unroll
      for (int ng = 0; ng < 2; ++ng)
#pragma unroll
        for (int d = 0; d < 3; ++d) {
          accP[m][ng][d] =
              __builtin_amdgcn_mfma_f32_16x16x32_bf16(aWh[m], bh[ng][d], accP[m][ng][d], 0, 0, 0);
          accP[m][ng][d] =
              __builtin_amdgcn_mfma_f32_16x16x32_bf16(aWh[m], bl[ng][d], accP[m][ng][d], 0, 0, 0);
          accP[m][ng][d] =
              __builtin_amdgcn_mfma_f32_16x16x32_bf16(aWl[m], bh[ng][d], accP[m][ng][d], 0, 0, 0);
          if (HAS_D) {
            accQ[m][ng][d] = __builtin_amdgcn_mfma_f32_16x16x32_bf16(aDh[m], bh[ng][d],
                                                                     accQ[m][ng][d], 0, 0, 0);
            accQ[m][ng][d] = __builtin_amdgcn_mfma_f32_16x16x32_bf16(aDh[m], bl[ng][d],
                                                                     accQ[m][ng][d], 0, 0, 0);
            accQ[m][ng][d] = __builtin_amdgcn_mfma_f32_16x16x32_bf16(aDl[m], bh[ng][d],
                                                                     accQ[m][ng][d], 0, 0, 0);
          }
        }
  }
#pragma unroll
  for (int m = 0; m < 2; ++m) {
    int cob = co0 + wm * 32 + m * 16 + lq * 4;
#pragma unroll
    for (int ng = 0; ng < 2; ++ng) {
      int n = n0 + wn * 32 + ng * 16 + lr;
      float qd0 = 0.f, qd1 = 0.f, qd2 = 0.f;
      if (!HAS_D) {
        qd0 = qbuf[((long)b * 3 + 0) * 2048 + n];
        qd1 = qbuf[((long)b * 3 + 1) * 2048 + n];
        qd2 = qbuf[((long)b * 3 + 2) * 2048 + n];
      }
      float yv[3][4];
#pragma unroll
      for (int r = 0; r < 4; ++r) {
        int co = cob + r;
        float p0 = accP[m][ng][0][r], p1 = accP[m][ng][1][r], p2 = accP[m][ng][2][r];
        float q0, q1, q2;
        if (HAS_D) {
          q0 = accQ[m][ng][0][r]; q1 = accQ[m][ng][1][r]; q2 = accQ[m][ng][2][r];
        } else {
          q0 = qd0; q1 = qd1; q2 = qd2;
        }
        if (HAS_BIAS) {
          const float* bp = biasP + ((long)b * 384 + co) * 3;
          p0 += bp[0]; p1 += bp[1]; p2 += bp[2];
          const float* bq = biasQ + ((long)b * 384 + co) * 3;
          q0 += bq[0]; q1 += bq[1]; q2 += bq[2];
        }
        float dot = p0 * q0 + p1 * q1 + p2 * q2;
        float dsq = q0 * q0 + q1 * q1 + q2 * q2;
        float coef = dot < 0.f ? 0.8f * dot / (dsq + EPSF) : 0.f;
        yv[0][r] = p0 - coef * q0;
        yv[1][r] = p1 - coef * q1;
        yv[2][r] = p2 - coef * q2;
        if (WF32 && co < Co) {
          float* yb = Yf + ((long)b * Co + co) * 6144 + n;
          yb[0] = yv[0][r];
          yb[2048] = yv[1][r];
          yb[4096] = yv[2][r];
        }
      }
      if (WT && cob < COPn) {
#pragma unroll
        for (int d = 0; d < 3; ++d) {
          u16 hh[4], ll[4];
#pragma unroll
          for (int r = 0; r < 4; ++r) {
            hh[r] = f2bf(yv[d][r]);
            ll[r] = f2bf(yv[d][r] - bf2f(hh[r]));
          }
          long rowa = ((long)b * 6144 + d * 2048 + n) * COPn + cob;
          uint2 vh, vl2;
          vh.x = (unsigned)hh[0] | ((unsigned)hh[1] << 16);
          vh.y = (unsigned)hh[2] | ((unsigned)hh[3] << 16);
          vl2.x = (unsigned)ll[0] | ((unsigned)ll[1] << 16);
          vl2.y = (unsigned)ll[2] | ((unsigned)ll[3] << 16);
          *(uint2*)(Yth + rowa) = vh;
          *(uint2*)(Ytl + rowa) = vl2;
        }
      }
    }
  }
}

// ---------------- row means of x5 ------------------------------------------
__global__ __launch_bounds__(256) void k_mean(const float* __restrict__ X,
                                              float* __restrict__ M) {
  long row = blockIdx.x;
  const float* xr = X + row * (long)NP;
  float s = 0.f;
  for (int n = threadIdx.x; n < NP; n += 256) s += xr[n];
  __shared__ float red[256];
  red[threadIdx.x] = s;
  __syncthreads();
  for (int st = 128; st > 0; st >>= 1) {
    if (threadIdx.x < st) red[threadIdx.x] += red[threadIdx.x + st];
    __syncthreads();
  }
  if (threadIdx.x == 0) M[row] = red[0] * (1.f / NP);
}

// ---------------- final fold + lrelu + mean ---------------------------------
__global__ __launch_bounds__(256) void k_final(const float* __restrict__ x5,
                                               const float* __restrict__ x5m,
                                               const float* __restrict__ z2,
                                               const float* __restrict__ Wlin,
                                               const float* __restrict__ W6,
                                               const float* __restrict__ D6,
                                               float* __restrict__ part) {
  int b = blockIdx.x >> 5;
  int chunk = blockIdx.x & 31;
  int w = threadIdx.x >> 6, lane = threadIdx.x & 63;
  int n = chunk * 64 + lane;
  __shared__ float W6s[3 * 682];
  __shared__ float D6s[682];
  __shared__ float Wls[3 * 170];
  __shared__ float red[4][64][22];
  for (int e = threadIdx.x; e < 3 * 682; e += 256) W6s[e] = W6[e];
  for (int e = threadIdx.x; e < 682; e += 256) D6s[e] = D6[e];
  for (int e = threadIdx.x; e < 3 * 170; e += 256) Wls[e] = Wlin[e];
  __syncthreads();
  const float* x5b = x5 + (long)b * 341 * 3 * NP;
  const float* z2b = z2 + (long)b * 170 * 3 * NP;
  const float* mb = x5m + (long)b * 341 * 3;
  float G[9] = {0, 0, 0, 0, 0, 0, 0, 0, 0};
  float H[3] = {0, 0, 0};
  float Z[9] = {0, 0, 0, 0, 0, 0, 0, 0, 0};
  int i0 = w * 171, i1 = min(682, i0 + 171);
  for (int i = i0; i < i1; ++i) {
    float v0, v1, v2;
    if (i < 341) {
      const float* p = x5b + (long)i * 3 * NP + n;
      v0 = p[0]; v1 = p[NP]; v2 = p[2 * NP];
    } else {
      const float* p = mb + (i - 341) * 3;
      v0 = p[0]; v1 = p[1]; v2 = p[2];
    }
    float w0 = W6s[i], w1 = W6s[682 + i], w2 = W6s[2 * 682 + i];
    G[0] += w0 * v0; G[1] += w0 * v1; G[2] += w0 * v2;
    G[3] += w1 * v0; G[4] += w1 * v1; G[5] += w1 * v2;
    G[6] += w2 * v0; G[7] += w2 * v1; G[8] += w2 * v2;
    float wd = D6s[i];
    H[0] += wd * v0; H[1] += wd * v1; H[2] += wd * v2;
  }
  int c0 = w * 43, c1 = min(170, c0 + 43);
  for (int c = c0; c < c1; ++c) {
    const float* p = z2b + (long)c * 3 * NP + n;
    float u0 = p[0], u1 = p[NP], u2 = p[2 * NP];
    float w0 = Wls[c], w1 = Wls[170 + c], w2 = Wls[2 * 170 + c];
    Z[0] += w0 * u0; Z[3] += w0 * u1; Z[6] += w0 * u2;
    Z[1] += w1 * u0; Z[4] += w1 * u1; Z[7] += w1 * u2;
    Z[2] += w2 * u0; Z[5] += w2 * u1; Z[8] += w2 * u2;
  }
  float* rp = red[w][lane];
#pragma unroll
  for (int q = 0; q < 9; ++q) rp[q] = G[q];
#pragma unroll
  for (int q = 0; q < 3; ++q) rp[9 + q] = H[q];
#pragma unroll
  for (int q = 0; q < 9; ++q) rp[12 + q] = Z[q];
  __syncthreads();
  if (w == 0) {
#pragma unroll
    for (int q = 0; q < 9; ++q) G[q] += red[1][lane][q] + red[2][lane][q] + red[3][lane][q];
#pragma unroll
    for (int q = 0; q < 3; ++q)
      H[q] += red[1][lane][9 + q] + red[2][lane][9 + q] + red[3][lane][9 + q];
#pragma unroll
    for (int q = 0; q < 9; ++q)
      Z[q] += red[1][lane][12 + q] + red[2][lane][12 + q] + red[3][lane][12 + q];
    float dv0 = H[0] * Z[0] + H[1] * Z[3] + H[2] * Z[6];
    float dv1 = H[0] * Z[1] + H[1] * Z[4] + H[2] * Z[7];
    float dv2 = H[0] * Z[2] + H[1] * Z[5] + H[2] * Z[8];
    float dsq = dv0 * dv0 + dv1 * dv1 + dv2 * dv2;
    float res[9];
#pragma unroll
    for (int o = 0; o < 3; ++o) {
      float p0 = G[o * 3 + 0] * Z[0] + G[o * 3 + 1] * Z[3] + G[o * 3 + 2] * Z[6];
      float p1 = G[o * 3 + 0] * Z[1] + G[o * 3 + 1] * Z[4] + G[o * 3 + 2] * Z[7];
      float p2 = G[o * 3 + 0] * Z[2] + G[o * 3 + 1] * Z[5] + G[o * 3 + 2] * Z[8];
      float dot = p0 * dv0 + p1 * dv1 + p2 * dv2;
      float coef = dot < 0.f ? 0.8f * dot / (dsq + EPSF) : 0.f;
      res[o * 3 + 0] = p0 - coef * dv0;
      res[o * 3 + 1] = p1 - coef * dv1;
      res[o * 3 + 2] = p2 - coef * dv2;
    }
#pragma unroll
    for (int e = 0; e < 9; ++e) {
      float v = res[e];
      for (int off = 32; off >= 1; off >>= 1) v += __shfl_down(v, off);
      if (lane == 0) part[(long)blockIdx.x * 9 + e] = v;
    }
  }
}

__global__ __launch_bounds__(128) void k_reduce(const float* __restrict__ part,
                                                float* __restrict__ out) {
  int e = threadIdx.x;
  if (e < NB * 9) {
    int b = e / 9, r = e - b * 9;
    float s = 0.f;
    for (int c = 0; c < 32; ++c) s += part[((long)b * 32 + c) * 9 + r];
    out[e] = s * (1.f / NP);
  }
}

// ---------------------------------------------------------------------------
extern "C" void kernel_launch(void* const* d_in, const int* in_sizes, int n_in,
                              void* d_out, int out_size, void* d_ws, size_t ws_size,
                              hipStream_t stream) {
  (void)in_sizes; (void)n_in; (void)out_size;
  const float* x = (const float*)d_in[0];
  const float* W1 = (const float*)d_in[1];
  const float* D1 = (const float*)d_in[2];
  const float* W2 = (const float*)d_in[3];
  const float* D2 = (const float*)d_in[4];
  const float* W3 = (const float*)d_in[5];
  const float* D3w = (const float*)d_in[6];
  const float* W4 = (const float*)d_in[7];
  const float* D4 = (const float*)d_in[8];
  const float* W5 = (const float*)d_in[9];
  const float* D5 = (const float*)d_in[10];
  const float* Ws1 = (const float*)d_in[11];
  const float* Ds1 = (const float*)d_in[12];
  const float* Ws2 = (const float*)d_in[13];
  const float* Ds2 = (const float*)d_in[14];
  const float* Wlin = (const float*)d_in[15];
  const float* W6 = (const float*)d_in[16];
  const float* D6 = (const float*)d_in[17];

  // ---- workspace layout (float units) ----
  const long o_xT = 0;
  const long o_sq = 49152;
  const long o_idx = 65536;
  const long o_wcat = 393216;
  const long o_x5m = 532480;
  const long o_qbuf = 540672;
  const long o_biasP = 589824;
  const long o_biasQ = 599040;
  const long o_W5h = 608256;
  const long o_W5l = 645120;
  const long o_Ws1h = 681984;
  const long o_Ws1l = 749568;
  const long o_Ds1h = 817152;
  const long o_Ds1l = 884736;
  const long o_Ws2h = 952320;
  const long o_Ws2l = 986112;
  const long o_Ds2h = 1019904;
  const long o_Ds2l = 1053696;
  const long o_xcat = 1090560;
  const long o_xcTh = 9397248;
  const long o_xcTl = 14115840;
  const long o_nd = 18834432;
  const long o_x5Th = 35595264;
  const long o_x5Tl = 44246016;
  const long o_z1Th = 1090560;
  const long o_z1Tl = 9741312;
  const long o_z2 = 35595264;
  const long total_floats = 52896768;  // ~212 MB
  if (ws_size < (size_t)total_floats * 4) return;

  float* ws = (float*)d_ws;
  float* xT = ws + o_xT;
  float* sq = ws + o_sq;
  int* idx = (int*)(ws + o_idx);
  float* wc1 = ws + o_wcat;
  float* wc2 = ws + o_wcat + 128;
  float* wc3 = ws + o_wcat + 2048;
  float* wc4 = ws + o_wcat + 5632;
  float* part = ws + o_wcat;  // alias: wcatT dead after layer loop
  float* x5m = ws + o_x5m;
  float* qbuf = ws + o_qbuf;
  float* biasP = ws + o_biasP;
  float* biasQ = ws + o_biasQ;
  float* xcat = ws + o_xcat;
  float* nd = ws + o_nd;
  float* Ubuf = ws + o_nd;
  float* x5 = ws + o_nd;
  u16* xcTh = (u16*)(ws + o_xcTh);
  u16* xcTl = (u16*)(ws + o_xcTl);
  u16* x5Th = (u16*)(ws + o_x5Th);
  u16* x5Tl = (u16*)(ws + o_x5Tl);
  u16* z1Th = (u16*)(ws + o_z1Th);
  u16* z1Tl = (u16*)(ws + o_z1Tl);
  float* z2 = ws + o_z2;
  u16* W5h = (u16*)(ws + o_W5h);
  u16* W5l = (u16*)(ws + o_W5l);
  u16* Ws1h = (u16*)(ws + o_Ws1h);
  u16* Ws1l = (u16*)(ws + o_Ws1l);
  u16* Ds1h = (u16*)(ws + o_Ds1h);
  u16* Ds1l = (u16*)(ws + o_Ds1l);
  u16* Ws2h = (u16*)(ws + o_Ws2h);
  u16* Ws2l = (u16*)(ws + o_Ws2l);
  u16* Ds2h = (u16*)(ws + o_Ds2h);
  u16* Ds2l = (u16*)(ws + o_Ds2l);

  const long SBcat = 169L * 3 * NP;

  k_prep<<<(int)((SZ_PREP + 255) / 256), 256, 0, stream>>>(
      x, xT, W5, Ws1, Ds1, Ws2, Ds2, W5h, W5l, Ws1h, Ws1l, Ds1h, Ds1l, Ws2h, Ws2l, Ds2h, Ds2l,
      W1, D1, W2, D2, W3, D3w, W4, D4, wc1, wc2, wc3, wc4, xcTh, xcTl);

  const float* Xl[4] = {xT, xcat, xcat + 21L * 3 * NP, xcat + 42L * 3 * NP};
  long SBl[4] = {3L * NP, SBcat, SBcat, SBcat};
  int Cl[4] = {1, 21, 21, 42};
  int Col[4] = {21, 21, 42, 85};
  int c0l[4] = {0, 21, 42, 84};
  float* wcl[4] = {wc1, wc2, wc3, wc4};

  for (int l = 0; l < 4; ++l) {
    int C = Cl[l], Co = Col[l], R4 = 4 * Co, Dd3 = 3 * C;
    k_sqnorm<<<NB * NP / 256, 256, 0, stream>>>(Xl[l], SBl[l], Dd3, sq);
    dim3 kg(NP / 128, NP / 128, NB);
    if (Dd3 == 3)
      k_knn3<3><<<kg, 256, 0, stream>>>(Xl[l], SBl[l], sq, nd);
    else if (Dd3 == 63)
      k_knn3<63><<<kg, 256, 0, stream>>>(Xl[l], SBl[l], sq, nd);
    else
      k_knn3<126><<<kg, 256, 0, stream>>>(Xl[l], SBl[l], sq, nd);
    k_topk4<<<NB * NP / 4, 256, 0, stream>>>(nd, idx);
    k_gemm_u2<<<NB * NP / 64, 256, (size_t)C * 3 * 64 * 4, stream>>>(Xl[l], SBl[l], C, wcl[l],
                                                                     R4, Ubuf);
    k_edge<<<NB * NP / 4, 256, 0, stream>>>(Ubuf, R4, Co, idx, xcat + (long)c0l[l] * 3 * NP,
                                            SBcat, xcTh, xcTl, c0l[l]);
  }

  k_qd5<<<(NB * 3 * NP + 255) / 256, 256, 0, stream>>>(xcat, D5, qbuf);
  k_vnmfma<0, 0, 1, 1><<<dim3(32, 6, NB), 256, 0, stream>>>(
      W5h, W5l, nullptr, nullptr, xcTh, xcTl, 192, qbuf, nullptr, nullptr, 341, x5, x5Th, x5Tl,
      352);
  k_mean<<<NB * 341 * 3, 256, 0, stream>>>(x5, x5m);
  k_bias<<<NB * 1152 / 4, 256, 0, stream>>>(Ws1, x5m, biasP);
  k_bias<<<NB * 1152 / 4, 256, 0, stream>>>(Ds1, x5m, biasQ);
  k_vnmfma<1, 1, 0, 1><<<dim3(32, 6, NB), 256, 0, stream>>>(
      Ws1h, Ws1l, Ds1h, Ds1l, x5Th, x5Tl, 352, nullptr, biasP, biasQ, 341, nullptr, z1Th, z1Tl,
      352);
  k_vnmfma<1, 0, 1, 0><<<dim3(32, 3, NB), 256, 0, stream>>>(
      Ws2h, Ws2l, Ds2h, Ds2l, z1Th, z1Tl, 352, nullptr, nullptr, nullptr, 170, z2, nullptr,
      nullptr, 352);

  k_final<<<NB * 32, 256, 0, stream>>>(x5, x5m, z2, Wlin, W6, D6, part);
  k_reduce<<<1, 128, 0, stream>>>(part, (float*)d_out);
}